// Round 9
// baseline (498.909 us; speedup 1.0000x reference)
//
#include <hip/hip_runtime.h>
#include <hip/hip_fp16.h>
#include <math.h>

#define TSZ2 4096
#define RMAXF 2.0f
#define NBAS 10
#define HID 100
#define SCB 1024   // scan elements per block
#define CHK 4096   // edges per binning block
#define KNODE 4    // nodes per wave in k_aggupd

__device__ __forceinline__ float sigmoidf_(float z) { return 1.0f / (1.0f + __expf(-z)); }
__device__ __forceinline__ float2 unp_h2(unsigned u) {
    __half2 h = __builtin_bit_cast(__half2, u);
    return __half22float2(h);
}
__device__ __forceinline__ unsigned pk_h2(float a, float b) {
    return __builtin_bit_cast(unsigned, __floats2half2_rn(a, b));
}

// ---------------- radial table fused with packing: tb2[l][t][c] {h2(w0,w1), h2(w2,0)} ----------------
// also zeroes cnt/bhist (runs before k_hist)
__global__ void k_table(const float* __restrict__ w1, const float* __restrict__ b1,
                        const float* __restrict__ w2, uint2* __restrict__ tb2,
                        int* __restrict__ cnt, int* __restrict__ bhist, int N) {
    int gtid = blockIdx.x * 256 + threadIdx.x;
    for (int i = gtid; i < N; i += gridDim.x * 256) cnt[i] = 0;
    if (gtid < 512) bhist[gtid] = 0;

    int l = blockIdx.x >> 7;
    int t0 = (blockIdx.x & 127) * 32;
    __shared__ float emb[32][NBAS];
    __shared__ float h[32][HID];
    __shared__ float w2s[HID * 48];
    __shared__ float wout[32][48];
    int tid = threadIdx.x;
    for (int i = tid; i < HID * 48; i += 256) w2s[i] = w2[l * HID * 48 + i];
    for (int i = tid; i < 32 * NBAS; i += 256) {
        int tt = i / NBAS, bi = i % NBAS;
        float r = (16.0f * (t0 + tt) + 7.5f) * (RMAXF / 65535.0f);
        float d = (r - (bi + 0.5f) * 0.2f) * 5.0f;
        emb[tt][bi] = (fabsf(d) < 1.0f) ? cosf(1.5707963267948966f * d) * 3.1622776601683795f : 0.0f;
    }
    __syncthreads();
    for (int i = tid; i < 32 * HID; i += 256) {
        int tt = i / HID, hh = i % HID;
        float z = b1[l * HID + hh];
        #pragma unroll
        for (int bi = 0; bi < NBAS; ++bi) z += emb[tt][bi] * w1[(l * NBAS + bi) * HID + hh];
        h[tt][hh] = z * sigmoidf_(z);
    }
    __syncthreads();
    for (int i = tid; i < 32 * 48; i += 256) {
        int tt = i / 48, j = i % 48;
        float o = 0.0f;
        for (int k = 0; k < HID; ++k) o += h[tt][k] * w2s[k * 48 + j];
        wout[tt][j] = o;
    }
    __syncthreads();
    for (int i = tid; i < 32 * 16; i += 256) {
        int tt = i >> 4, c = i & 15;
        int t = t0 + tt;
        uint2 o = make_uint2(0, 0);
        if (t != TSZ2 - 1) {   // last row stays zero = sentinel
            o.x = pk_h2(wout[tt][c], wout[tt][16 + c]);
            o.y = pk_h2(wout[tt][32 + c], 0.0f);
        }
        tb2[((size_t)l * TSZ2 + t) * 16 + c] = o;
    }
}

// ---------------- histogram: per-node (global atomics) + per-bucket (LDS-agg) ----------------
__global__ void k_hist(const int* __restrict__ edst, int* cnt, int* bhist, int E) {
    __shared__ int lb[512];
    int tid = threadIdx.x;
    for (int i = tid; i < 512; i += 256) lb[i] = 0;
    __syncthreads();
    int e0 = blockIdx.x * CHK;
    #pragma unroll
    for (int k = 0; k < CHK / 256; ++k) {
        int e = e0 + k * 256 + tid;
        if (e < E) {
            int d = edst[e];
            atomicAdd(&cnt[d], 1);
            atomicAdd(&lb[d >> 7], 1);
        }
    }
    __syncthreads();
    for (int i = tid; i < 512; i += 256) if (lb[i]) atomicAdd(&bhist[i], lb[i]);
}

// ---------------- bucket scan (1 block, 512 threads) ----------------
__global__ void k_bscan(const int* __restrict__ bhist, int* __restrict__ bbase,
                        int* __restrict__ bcursor, int nbuck, int E) {
    __shared__ int part[512];
    int t = threadIdx.x;
    part[t] = (t < nbuck) ? bhist[t] : 0;
    __syncthreads();
    for (int off = 1; off < 512; off <<= 1) {
        int v = (t >= off) ? part[t - off] : 0;
        __syncthreads();
        part[t] += v;
        __syncthreads();
    }
    int ex = (t == 0) ? 0 : part[t - 1];
    if (t < nbuck) { bbase[t] = ex; bcursor[t] = ex; }
    if (t == 0) bbase[nbuck] = E;
}

// ---------------- node-level scans (padded to 8) ----------------
__global__ void k_scanA(const int* __restrict__ cnt, int* __restrict__ bsum, int N) {
    __shared__ int red[256];
    int base = blockIdx.x * SCB;
    int t = threadIdx.x;
    int s = 0;
    #pragma unroll
    for (int k = 0; k < 4; ++k) {
        int i = base + k * 256 + t;
        if (i < N) s += (cnt[i] + 7) & ~7;
    }
    red[t] = s;
    __syncthreads();
    for (int off = 128; off > 0; off >>= 1) {
        if (t < off) red[t] += red[t + off];
        __syncthreads();
    }
    if (t == 0) bsum[blockIdx.x] = red[0];
}

__global__ void k_scanB(const int* __restrict__ bsum, int* __restrict__ boff, int nb) {
    __shared__ int part[256];
    int t = threadIdx.x;
    part[t] = (t < nb) ? bsum[t] : 0;
    __syncthreads();
    for (int off = 1; off < 256; off <<= 1) {
        int v = (t >= off) ? part[t - off] : 0;
        __syncthreads();
        part[t] += v;
        __syncthreads();
    }
    boff[t] = (t == 0) ? 0 : part[t - 1];
}

__global__ void k_scanC(const int* __restrict__ cnt, const int* __restrict__ boff,
                        int* __restrict__ row_start, int* __restrict__ cursor, int N) {
    __shared__ int part[256];
    int b = blockIdx.x, t = threadIdx.x;
    int base = b * SCB;
    int v[4];
    int s = 0;
    #pragma unroll
    for (int k = 0; k < 4; ++k) {
        int i = base + t * 4 + k;
        v[k] = (i < N) ? ((cnt[i] + 7) & ~7) : 0;
        s += v[k];
    }
    part[t] = s;
    __syncthreads();
    for (int off = 1; off < 256; off <<= 1) {
        int x = (t >= off) ? part[t - off] : 0;
        __syncthreads();
        part[t] += x;
        __syncthreads();
    }
    int run = boff[b] + ((t == 0) ? 0 : part[t - 1]);
    #pragma unroll
    for (int k = 0; k < 4; ++k) {
        int i = base + t * 4 + k;
        if (i < N) {
            row_start[i] = run; cursor[i] = run; run += v[k];
            if (i == N - 1) row_start[N] = run;
        }
    }
}

// ---------------- phase 1: bin edges into dst-buckets with geometry, burst writes ----------------
__global__ void k_scat1(const float* __restrict__ pos, const int* __restrict__ esrc,
                        const int* __restrict__ edst, int* __restrict__ bcursor,
                        uint4* __restrict__ bbuf, int E, int nbuck) {
    __shared__ int lcnt[512];
    __shared__ int base[512];
    int tid = threadIdx.x;
    for (int i = tid; i < 512; i += 256) lcnt[i] = 0;
    __syncthreads();
    int e0 = blockIdx.x * CHK;
    #pragma unroll
    for (int k = 0; k < CHK / 256; ++k) {
        int e = e0 + k * 256 + tid;
        if (e < E) atomicAdd(&lcnt[edst[e] >> 7], 1);
    }
    __syncthreads();
    for (int b = tid; b < nbuck; b += 256)
        base[b] = lcnt[b] ? atomicAdd(&bcursor[b], lcnt[b]) : 0;
    __syncthreads();
    #pragma unroll
    for (int k = 0; k < CHK / 256; ++k) {
        int e = e0 + k * 256 + tid;
        if (e >= E) continue;
        int s = esrc[e], d = edst[e];
        float vx = pos[s * 3 + 0] - pos[d * 3 + 0];
        float vy = pos[s * 3 + 1] - pos[d * 3 + 1];
        float vz = pos[s * 3 + 2] - pos[d * 3 + 2];
        float r = sqrtf(vx * vx + vy * vy + vz * vz);
        float kf = 1.7320508075688772f / (r + 1e-12f);   // sqrt(3)/r premult
        unsigned rtfix = (unsigned)fminf(r * (65535.0f / RMAXF) + 0.5f, 65535.0f);
        uint4 o;
        o.x = (unsigned)s | (rtfix << 16);
        o.y = pk_h2(vx * kf, vy * kf);
        o.z = __float_as_uint(vz * kf);
        o.w = (unsigned)d;
        int slot = atomicAdd(&base[d >> 7], 1);
        bbuf[slot] = o;
    }
}

// ---------------- phase 2: bucket -> exact CSR slot + sentinel padfill (fused) ----------------
__global__ void k_scat2(const uint4* __restrict__ bbuf, const int* __restrict__ bbase,
                        int* __restrict__ cursor, const int* __restrict__ row_start,
                        uint4* __restrict__ csr, int N) {
    int b = blockIdx.x;
    int j0 = bbase[b], j1 = bbase[b + 1];
    for (int j = j0 + threadIdx.x; j < j1; j += 256) {
        uint4 e = bbuf[j];
        int d = (int)e.w;
        int slot = atomicAdd(&cursor[d], 1);
        csr[slot] = e;
    }
    __syncthreads();
    int n0 = b << 7, n1 = min(n0 + 128, N);
    uint4 sent = make_uint4(0xFFFF0000u, 0, 0, 0);
    for (int n = n0 + threadIdx.x; n < n1; n += 256) {
        int s1 = row_start[n + 1];
        for (int s = cursor[n]; s < s1; ++s) csr[s] = sent;
    }
}

// ---------------- p0 = x0 @ P0[0] (layer 0 only) ----------------
__global__ void k_p0(const float* __restrict__ x0, const float* __restrict__ P0l,
                     float* __restrict__ p0, int N) {
    int i = blockIdx.x * blockDim.x + threadIdx.x;
    if (i >= N * 16) return;
    int n = i >> 4, m = i & 15;
    float acc = 0.0f;
    #pragma unroll
    for (int c = 0; c < 16; ++c) acc += x0[n * 16 + c] * P0l[c * 16 + m];
    p0[i] = acc;
}

// ---------------- fused aggregation + node update; KNODE nodes per wave, dbuf DMA pipeline ----------------
__launch_bounds__(256)
__global__ void k_aggupd(const int* __restrict__ row_start, const uint4* __restrict__ csr,
                         const uint2* __restrict__ tb2, const float* __restrict__ p0g,
                         const float* __restrict__ x0c, const float* __restrict__ x1c,
                         const float* __restrict__ x2c,
                         float* __restrict__ x0n, float* __restrict__ x1n, float* __restrict__ x2n,
                         float* __restrict__ p0out,
                         const float* __restrict__ Wsc, const float* __restrict__ Wa,
                         const float* __restrict__ W1m, const float* __restrict__ W2m,
                         const float* __restrict__ P0n,
                         int N, int ldx12, int wp0) {
    const float INVS = 0.17677669529663687f;  // 1/sqrt(32)
    const float K1  = 1.2909944487358056f;    // sqrt(15)/3
    const float S5H = 1.118033988749895f;     // sqrt(5)/2
    const float K2  = 0.6454972243679028f;    // sqrt(15)/2/3
    __shared__ uint4 ROW[4][2][144];
    __shared__ float XIN[4][2][144];
    __shared__ float AGG[4][144];
    int tid = threadIdx.x;
    int wid = tid >> 6;
    int lane = tid & 63;
    int g = lane >> 4, c = lane & 15;
    int nbase = (blockIdx.x * 4 + wid) * KNODE;
    int nxin = ldx12 ? 36 : 4;

    // preload row bounds for this wave's nodes (lane i holds row_start[nbase+i])
    int rsv = 0;
    if (lane <= KNODE) {
        int idx = nbase + lane;
        rsv = row_start[idx < N ? idx : N];
    }

    auto STAGE = [&](int i, int buf) {
        int n = nbase + i; if (n > N - 1) n = N - 1;
        int e0 = __shfl(rsv, i);
        __builtin_amdgcn_global_load_lds(
            (const __attribute__((address_space(1))) void*)(csr + e0 + lane),
            (__attribute__((address_space(3))) void*)(&ROW[wid][buf][0]), 16, 0, 0);
        __builtin_amdgcn_global_load_lds(
            (const __attribute__((address_space(1))) void*)(csr + e0 + 64 + lane),
            (__attribute__((address_space(3))) void*)(&ROW[wid][buf][64]), 16, 0, 0);
        const float* src;
        if (lane < 4)       src = x0c + (size_t)n * 16 + lane * 4;
        else if (lane < 16) src = x1c + (size_t)n * 48 + (lane - 4) * 4;
        else                src = x2c + (size_t)n * 80 + (lane - 16) * 4;
        if (lane < nxin)
            __builtin_amdgcn_global_load_lds(
                (const __attribute__((address_space(1))) void*)src,
                (__attribute__((address_space(3))) void*)(&XIN[wid][buf][0]), 16, 0, 0);
    };

    STAGE(0, 0);
    for (int i = 0; i < KNODE; ++i) {
        int buf = i & 1;
        if (i + 1 < KNODE) {
            STAGE(i + 1, buf ^ 1);
            asm volatile("s_waitcnt vmcnt(3)" ::: "memory");   // node i's DMA done; i+1 in flight
        } else {
            asm volatile("s_waitcnt vmcnt(0)" ::: "memory");
        }
        int n = nbase + i;
        float a0 = 0, a10 = 0, a11 = 0, a12 = 0, a20 = 0, a21 = 0, a22 = 0, a23 = 0, a24 = 0;
        auto EDGE = [&](uint4 cv, float pv, uint2 Tv) {
            float2 uxy = unp_h2(cv.y);
            float ux = uxy.x, uy = uxy.y, uz = __uint_as_float(cv.z);
            float2 w01 = unp_h2(Tv.x);
            float2 w2_ = unp_h2(Tv.y);
            float sh20 = K1 * (ux * uy);
            float sh21 = K1 * (uy * uz);
            float sh22 = S5H * (uz * uz - 1.0f);
            float sh23 = K1 * (ux * uz);
            float sh24 = K2 * (ux * ux - uy * uy);
            a0 += w01.x * pv;
            float w1p = w01.y * pv, w2p = w2_.x * pv;
            a10 += w1p * ux; a11 += w1p * uy; a12 += w1p * uz;
            a20 += w2p * sh20; a21 += w2p * sh21; a22 += w2p * sh22;
            a23 += w2p * sh23; a24 += w2p * sh24;
        };
        if (n < N) {
            int e0 = __shfl(rsv, i);
            int plen = __shfl(rsv, i + 1) - e0;
            if (plen > 0) {
                const uint4* RB = &ROW[wid][buf][0];
                int L = (plen + 3) >> 2;          // padded rows: L even
                int Lm = L < 32 ? L : 32;
                uint4 c0 = RB[g], c1 = RB[4 + g], c2 = RB[8 + g], c3 = RB[12 + g];
                float p0v = p0g[(c0.x & 0xffffu) * 16 + c]; uint2 T0 = tb2[((c0.x >> 16) & 0xfff0u) | c];
                float p1v = p0g[(c1.x & 0xffffu) * 16 + c]; uint2 T1 = tb2[((c1.x >> 16) & 0xfff0u) | c];
                float p2v = p0g[(c2.x & 0xffffu) * 16 + c]; uint2 T2 = tb2[((c2.x >> 16) & 0xfff0u) | c];
                #pragma unroll 2
                for (int k = 0; k < Lm; ++k) {
                    uint4 c4 = RB[(k + 4) * 4 + g];
                    float p3v = p0g[(c3.x & 0xffffu) * 16 + c];
                    uint2 T3  = tb2[((c3.x >> 16) & 0xfff0u) | c];
                    EDGE(c0, p0v, T0);
                    c0 = c1; c1 = c2; c2 = c3; c3 = c4;
                    p0v = p1v; T0 = T1; p1v = p2v; T1 = T2; p2v = p3v; T2 = T3;
                }
                if (plen > 128) {   // rare fallback beyond LDS window
                    for (int j = e0 + 128 + g; j < e0 + plen; j += 4) {
                        uint4 cx = csr[j];
                        float pv = p0g[(cx.x & 0xffffu) * 16 + c];
                        uint2 Tx = tb2[((cx.x >> 16) & 0xfff0u) | c];
                        EDGE(cx, pv, Tx);
                    }
                }
            }
        }
        #pragma unroll
        for (int m = 16; m < 64; m <<= 1) {
            a0  += __shfl_xor(a0, m);
            a10 += __shfl_xor(a10, m); a11 += __shfl_xor(a11, m); a12 += __shfl_xor(a12, m);
            a20 += __shfl_xor(a20, m); a21 += __shfl_xor(a21, m); a22 += __shfl_xor(a22, m);
            a23 += __shfl_xor(a23, m); a24 += __shfl_xor(a24, m);
        }
        if (n < N) {
            float* A = AGG[wid];
            if (lane < 16) {
                A[c] = a0 * INVS;
                A[16 + c * 3 + 0] = a10 * INVS; A[16 + c * 3 + 1] = a11 * INVS; A[16 + c * 3 + 2] = a12 * INVS;
                A[64 + c * 5 + 0] = a20 * INVS; A[64 + c * 5 + 1] = a21 * INVS; A[64 + c * 5 + 2] = a22 * INVS;
                A[64 + c * 5 + 3] = a23 * INVS; A[64 + c * 5 + 4] = a24 * INVS;
            }
            // wave-synchronous: same-wave DS ops are in-order; no __syncthreads needed
            const float* X = &XIN[wid][buf][0];
            float act = 0.0f;
            if (lane < 48) {
                float sj = 0.0f;
                #pragma unroll
                for (int cc = 0; cc < 16; ++cc)
                    sj += X[cc] * Wsc[cc * 48 + lane] + A[cc] * Wa[cc * 48 + lane];
                float sg = sigmoidf_(sj);
                act = (lane < 16) ? sj * sg : sg;
            }
            if (lane < 16) x0n[n * 16 + lane] = act;
            if (wp0) {
                float pn = 0.0f;
                #pragma unroll
                for (int cc = 0; cc < 16; ++cc) pn += __shfl(act, cc) * P0n[cc * 16 + (lane & 15)];
                if (lane < 16) p0out[n * 16 + lane] = pn;
            }
            {
                int d = lane >> 4, m = lane & 15;
                float v = 0.0f;
                if (lane < 48) {
                    if (ldx12) {
                        #pragma unroll
                        for (int cc = 0; cc < 16; ++cc) v += X[16 + cc * 3 + d] * W1m[cc * 16 + m];
                    }
                    v += A[16 + m * 3 + d];
                }
                float sg1 = __shfl(act, 16 + m);
                if (lane < 48) x1n[(size_t)n * 48 + m * 3 + d] = v * sg1;
            }
            #pragma unroll
            for (int ch = 0; ch < 2; ++ch) {
                int idx = ch * 64 + lane;
                int d = idx >> 4, m = idx & 15;
                bool on = idx < 80;
                float v = 0.0f;
                if (on) {
                    if (ldx12) {
                        #pragma unroll
                        for (int cc = 0; cc < 16; ++cc) v += X[64 + cc * 5 + d] * W2m[cc * 16 + m];
                    }
                    v += A[64 + m * 5 + d];
                }
                float sg2 = __shfl(act, 32 + (m & 15));
                if (on) x2n[(size_t)n * 80 + m * 5 + d] = v * sg2;
            }
        }
    }
}

// ---------------- final reduction ----------------
__global__ void k_out1(const float* __restrict__ x0, const float* __restrict__ Wout,
                       float* __restrict__ partial, int N) {
    __shared__ float red[256];
    int tid = threadIdx.x;
    float s = 0.0f;
    for (int n = blockIdx.x * blockDim.x + tid; n < N; n += gridDim.x * blockDim.x) {
        float acc = 0.0f;
        #pragma unroll
        for (int cc = 0; cc < 16; ++cc) acc += x0[n * 16 + cc] * Wout[cc];
        s += acc;
    }
    red[tid] = s;
    __syncthreads();
    for (int off = 128; off > 0; off >>= 1) {
        if (tid < off) red[tid] += red[tid + off];
        __syncthreads();
    }
    if (tid == 0) partial[blockIdx.x] = red[0];
}

__global__ void k_out2(const float* __restrict__ partial, float* __restrict__ out,
                       int nb, float scale) {
    __shared__ float red[256];
    int tid = threadIdx.x;
    red[tid] = (tid < nb) ? partial[tid] : 0.0f;
    __syncthreads();
    for (int off = 128; off > 0; off >>= 1) {
        if (tid < off) red[tid] += red[tid + off];
        __syncthreads();
    }
    if (tid == 0) out[0] = red[0] * scale;
}

extern "C" void kernel_launch(void* const* d_in, const int* in_sizes, int n_in,
                              void* d_out, int out_size, void* d_ws, size_t ws_size,
                              hipStream_t stream) {
    const float* pos = (const float*)d_in[0];
    const float* x   = (const float*)d_in[1];
    const int* esrc  = (const int*)d_in[2];
    const int* edst  = (const int*)d_in[3];
    const float* mlp_w1 = (const float*)d_in[5];
    const float* mlp_b1 = (const float*)d_in[6];
    const float* mlp_w2 = (const float*)d_in[7];
    const float* P0  = (const float*)d_in[8];
    const float* Wsc = (const float*)d_in[9];
    const float* Wa  = (const float*)d_in[10];
    const float* W1m = (const float*)d_in[11];
    const float* W2m = (const float*)d_in[12];
    const float* Wout = (const float*)d_in[13];
    int N = in_sizes[0] / 3;
    int E = in_sizes[2];
    int cap = E + 8 * N + 256;
    int nbuck = (N + 127) >> 7;

    char* ws = (char*)d_ws;
    size_t off = 0;
    auto alloc = [&](size_t bytes) -> void* {
        void* p = ws + off;
        off += (bytes + 255) & ~(size_t)255;
        return p;
    };
    int*    cnt       = (int*)alloc((size_t)N * 4);
    int*    row_start = (int*)alloc((size_t)(N + 1) * 4);
    int*    cursor    = (int*)alloc((size_t)N * 4);
    int*    bsum      = (int*)alloc(256 * 4);
    int*    boff      = (int*)alloc(256 * 4);
    int*    bhist     = (int*)alloc(512 * 4);
    int*    bbase     = (int*)alloc(513 * 4);
    int*    bcursor   = (int*)alloc(512 * 4);
    uint4*  csr       = (uint4*)alloc((size_t)cap * 16);
    uint2*  tb2       = (uint2*)alloc((size_t)3 * TSZ2 * 16 * 8);
    float*  p0A = (float*)alloc((size_t)65536 * 16 * 4);   // src is 16-bit
    float*  p0B = (float*)alloc((size_t)65536 * 16 * 4);
    float*  x0A = (float*)alloc((size_t)N * 16 * 4);
    float*  x0B = (float*)alloc((size_t)N * 16 * 4);
    float*  x1B = (float*)alloc((size_t)N * 48 * 4);
    float*  x2B = (float*)alloc((size_t)N * 80 * 4);
    // union region: bbuf (setup-only) aliases x1A + x2A (first written in layer 1)
    size_t x1Asz = ((size_t)N * 48 * 4 + 255) & ~(size_t)255;
    size_t unionSz = x1Asz + (size_t)N * 80 * 4;
    size_t bbufSz = (size_t)E * 16;
    char*  unionA = (char*)alloc(unionSz > bbufSz ? unionSz : bbufSz);
    float* x1A = (float*)unionA;
    float* x2A = (float*)(unionA + x1Asz);
    uint4* bbuf = (uint4*)unionA;
    float*  partial = (float*)alloc(256 * 4);

    int nbscan = (N + SCB - 1) / SCB;
    int nchunk = (E + CHK - 1) / CHK;

    k_table<<<3 * (TSZ2 / 32), 256, 0, stream>>>(mlp_w1, mlp_b1, mlp_w2, tb2, cnt, bhist, N);
    k_hist<<<nchunk, 256, 0, stream>>>(edst, cnt, bhist, E);
    k_scanA<<<nbscan, 256, 0, stream>>>(cnt, bsum, N);
    k_scanB<<<1, 256, 0, stream>>>(bsum, boff, nbscan);
    k_scanC<<<nbscan, 256, 0, stream>>>(cnt, boff, row_start, cursor, N);
    k_bscan<<<1, 512, 0, stream>>>(bhist, bbase, bcursor, nbuck, E);
    k_scat1<<<nchunk, 256, 0, stream>>>(pos, esrc, edst, bcursor, bbuf, E, nbuck);
    k_scat2<<<nbuck, 256, 0, stream>>>(bbuf, bbase, cursor, row_start, csr, N);
    k_p0<<<(N * 16 + 255) / 256, 256, 0, stream>>>(x, P0, p0A, N);

    float* x0bufs[2] = {x0A, x0B};
    float* x1bufs[2] = {x1A, x1B};
    float* x2bufs[2] = {x2A, x2B};
    float* p0bufs[2] = {p0A, p0B};
    int nwave = 4 * KNODE;   // nodes per block
    for (int l = 0; l < 3; ++l) {
        const float* x0c = (l == 0) ? x : x0bufs[l & 1];
        const float* x1c = x1bufs[l & 1];
        const float* x2c = x2bufs[l & 1];
        float* x0n = x0bufs[(l & 1) ^ 1];
        float* x1n = x1bufs[(l & 1) ^ 1];
        float* x2n = x2bufs[(l & 1) ^ 1];
        const float* p0c = p0bufs[l & 1];
        float* p0n = p0bufs[(l & 1) ^ 1];
        const float* P0next = (l < 2) ? (P0 + (l + 1) * 256) : P0;
        k_aggupd<<<(N + nwave - 1) / nwave, 256, 0, stream>>>(
            row_start, csr, tb2 + (size_t)l * TSZ2 * 16, p0c,
            x0c, x1c, x2c, x0n, x1n, x2n, p0n,
            Wsc + l * 768, Wa + l * 768,
            W1m + l * 256, W2m + l * 256, P0next, N,
            (l == 0) ? 0 : 1, (l < 2) ? 1 : 0);
    }
    float scale = (float)(1.0 / sqrt((double)N));
    k_out1<<<256, 256, 0, stream>>>(x0bufs[1], Wout, partial, N);
    k_out2<<<1, 256, 0, stream>>>(partial, (float*)d_out, 256, scale);
}

// Round 10
// 453.152 us; speedup vs baseline: 1.1010x; 1.1010x over previous
//
#include <hip/hip_runtime.h>
#include <hip/hip_fp16.h>
#include <math.h>

#define TSZ2 4096
#define RMAXF 2.0f
#define NBAS 10
#define HID 100
#define SCB 1024   // scan elements per block
#define CHK 4096   // edges per binning block
#define KNODE 4    // nodes per wave in k_aggupd

__device__ __forceinline__ float sigmoidf_(float z) { return 1.0f / (1.0f + __expf(-z)); }
__device__ __forceinline__ float2 unp_h2(unsigned u) {
    __half2 h = __builtin_bit_cast(__half2, u);
    return __half22float2(h);
}
__device__ __forceinline__ unsigned pk_h2(float a, float b) {
    return __builtin_bit_cast(unsigned, __floats2half2_rn(a, b));
}

// ---------------- radial table fused with packing: tb2[l][t][c] {h2(w0,w1), h2(w2,0)} ----------------
// also zeroes cnt/bhist (runs before k_hist)
__global__ void k_table(const float* __restrict__ w1, const float* __restrict__ b1,
                        const float* __restrict__ w2, uint2* __restrict__ tb2,
                        int* __restrict__ cnt, int* __restrict__ bhist, int N) {
    int gtid = blockIdx.x * 256 + threadIdx.x;
    for (int i = gtid; i < N; i += gridDim.x * 256) cnt[i] = 0;
    if (gtid < 512) bhist[gtid] = 0;

    int l = blockIdx.x >> 7;
    int t0 = (blockIdx.x & 127) * 32;
    __shared__ float emb[32][NBAS];
    __shared__ float h[32][HID];
    __shared__ float w2s[HID * 48];
    __shared__ float wout[32][48];
    int tid = threadIdx.x;
    for (int i = tid; i < HID * 48; i += 256) w2s[i] = w2[l * HID * 48 + i];
    for (int i = tid; i < 32 * NBAS; i += 256) {
        int tt = i / NBAS, bi = i % NBAS;
        float r = (16.0f * (t0 + tt) + 7.5f) * (RMAXF / 65535.0f);
        float d = (r - (bi + 0.5f) * 0.2f) * 5.0f;
        emb[tt][bi] = (fabsf(d) < 1.0f) ? cosf(1.5707963267948966f * d) * 3.1622776601683795f : 0.0f;
    }
    __syncthreads();
    for (int i = tid; i < 32 * HID; i += 256) {
        int tt = i / HID, hh = i % HID;
        float z = b1[l * HID + hh];
        #pragma unroll
        for (int bi = 0; bi < NBAS; ++bi) z += emb[tt][bi] * w1[(l * NBAS + bi) * HID + hh];
        h[tt][hh] = z * sigmoidf_(z);
    }
    __syncthreads();
    for (int i = tid; i < 32 * 48; i += 256) {
        int tt = i / 48, j = i % 48;
        float o = 0.0f;
        for (int k = 0; k < HID; ++k) o += h[tt][k] * w2s[k * 48 + j];
        wout[tt][j] = o;
    }
    __syncthreads();
    for (int i = tid; i < 32 * 16; i += 256) {
        int tt = i >> 4, c = i & 15;
        int t = t0 + tt;
        uint2 o = make_uint2(0, 0);
        if (t != TSZ2 - 1) {   // last row stays zero = sentinel
            o.x = pk_h2(wout[tt][c], wout[tt][16 + c]);
            o.y = pk_h2(wout[tt][32 + c], 0.0f);
        }
        tb2[((size_t)l * TSZ2 + t) * 16 + c] = o;
    }
}

// ---------------- histogram: per-node (global atomics) + per-bucket (LDS-agg) ----------------
__global__ void k_hist(const int* __restrict__ edst, int* cnt, int* bhist, int E) {
    __shared__ int lb[512];
    int tid = threadIdx.x;
    for (int i = tid; i < 512; i += 256) lb[i] = 0;
    __syncthreads();
    int e0 = blockIdx.x * CHK;
    #pragma unroll
    for (int k = 0; k < CHK / 256; ++k) {
        int e = e0 + k * 256 + tid;
        if (e < E) {
            int d = edst[e];
            atomicAdd(&cnt[d], 1);
            atomicAdd(&lb[d >> 7], 1);
        }
    }
    __syncthreads();
    for (int i = tid; i < 512; i += 256) if (lb[i]) atomicAdd(&bhist[i], lb[i]);
}

// ---------------- bucket scan (1 block, 512 threads) ----------------
__global__ void k_bscan(const int* __restrict__ bhist, int* __restrict__ bbase,
                        int* __restrict__ bcursor, int nbuck, int E) {
    __shared__ int part[512];
    int t = threadIdx.x;
    part[t] = (t < nbuck) ? bhist[t] : 0;
    __syncthreads();
    for (int off = 1; off < 512; off <<= 1) {
        int v = (t >= off) ? part[t - off] : 0;
        __syncthreads();
        part[t] += v;
        __syncthreads();
    }
    int ex = (t == 0) ? 0 : part[t - 1];
    if (t < nbuck) { bbase[t] = ex; bcursor[t] = ex; }
    if (t == 0) bbase[nbuck] = E;
}

// ---------------- node-level scans (padded to 8) ----------------
__global__ void k_scanA(const int* __restrict__ cnt, int* __restrict__ bsum, int N) {
    __shared__ int red[256];
    int base = blockIdx.x * SCB;
    int t = threadIdx.x;
    int s = 0;
    #pragma unroll
    for (int k = 0; k < 4; ++k) {
        int i = base + k * 256 + t;
        if (i < N) s += (cnt[i] + 7) & ~7;
    }
    red[t] = s;
    __syncthreads();
    for (int off = 128; off > 0; off >>= 1) {
        if (t < off) red[t] += red[t + off];
        __syncthreads();
    }
    if (t == 0) bsum[blockIdx.x] = red[0];
}

__global__ void k_scanB(const int* __restrict__ bsum, int* __restrict__ boff, int nb) {
    __shared__ int part[256];
    int t = threadIdx.x;
    part[t] = (t < nb) ? bsum[t] : 0;
    __syncthreads();
    for (int off = 1; off < 256; off <<= 1) {
        int v = (t >= off) ? part[t - off] : 0;
        __syncthreads();
        part[t] += v;
        __syncthreads();
    }
    boff[t] = (t == 0) ? 0 : part[t - 1];
}

__global__ void k_scanC(const int* __restrict__ cnt, const int* __restrict__ boff,
                        int* __restrict__ row_start, int* __restrict__ cursor, int N) {
    __shared__ int part[256];
    int b = blockIdx.x, t = threadIdx.x;
    int base = b * SCB;
    int v[4];
    int s = 0;
    #pragma unroll
    for (int k = 0; k < 4; ++k) {
        int i = base + t * 4 + k;
        v[k] = (i < N) ? ((cnt[i] + 7) & ~7) : 0;
        s += v[k];
    }
    part[t] = s;
    __syncthreads();
    for (int off = 1; off < 256; off <<= 1) {
        int x = (t >= off) ? part[t - off] : 0;
        __syncthreads();
        part[t] += x;
        __syncthreads();
    }
    int run = boff[b] + ((t == 0) ? 0 : part[t - 1]);
    #pragma unroll
    for (int k = 0; k < 4; ++k) {
        int i = base + t * 4 + k;
        if (i < N) {
            row_start[i] = run; cursor[i] = run; run += v[k];
            if (i == N - 1) row_start[N] = run;
        }
    }
}

// ---------------- phase 1: bin edges into dst-buckets with geometry, burst writes ----------------
__global__ void k_scat1(const float* __restrict__ pos, const int* __restrict__ esrc,
                        const int* __restrict__ edst, int* __restrict__ bcursor,
                        uint4* __restrict__ bbuf, int E, int nbuck) {
    __shared__ int lcnt[512];
    __shared__ int base[512];
    int tid = threadIdx.x;
    for (int i = tid; i < 512; i += 256) lcnt[i] = 0;
    __syncthreads();
    int e0 = blockIdx.x * CHK;
    #pragma unroll
    for (int k = 0; k < CHK / 256; ++k) {
        int e = e0 + k * 256 + tid;
        if (e < E) atomicAdd(&lcnt[edst[e] >> 7], 1);
    }
    __syncthreads();
    for (int b = tid; b < nbuck; b += 256)
        base[b] = lcnt[b] ? atomicAdd(&bcursor[b], lcnt[b]) : 0;
    __syncthreads();
    #pragma unroll
    for (int k = 0; k < CHK / 256; ++k) {
        int e = e0 + k * 256 + tid;
        if (e >= E) continue;
        int s = esrc[e], d = edst[e];
        float vx = pos[s * 3 + 0] - pos[d * 3 + 0];
        float vy = pos[s * 3 + 1] - pos[d * 3 + 1];
        float vz = pos[s * 3 + 2] - pos[d * 3 + 2];
        float r = sqrtf(vx * vx + vy * vy + vz * vz);
        float kf = 1.7320508075688772f / (r + 1e-12f);   // sqrt(3)/r premult
        unsigned rtfix = (unsigned)fminf(r * (65535.0f / RMAXF) + 0.5f, 65535.0f);
        uint4 o;
        o.x = (unsigned)s | (rtfix << 16);
        o.y = pk_h2(vx * kf, vy * kf);
        o.z = __float_as_uint(vz * kf);
        o.w = (unsigned)d;
        int slot = atomicAdd(&base[d >> 7], 1);
        bbuf[slot] = o;
    }
}

// ---------------- phase 2: bucket -> exact CSR slot + sentinel padfill (fused) ----------------
__global__ void k_scat2(const uint4* __restrict__ bbuf, const int* __restrict__ bbase,
                        int* __restrict__ cursor, const int* __restrict__ row_start,
                        uint4* __restrict__ csr, int N) {
    int b = blockIdx.x;
    int j0 = bbase[b], j1 = bbase[b + 1];
    for (int j = j0 + threadIdx.x; j < j1; j += 256) {
        uint4 e = bbuf[j];
        int d = (int)e.w;
        int slot = atomicAdd(&cursor[d], 1);
        csr[slot] = e;
    }
    __syncthreads();
    int n0 = b << 7, n1 = min(n0 + 128, N);
    uint4 sent = make_uint4(0xFFFF0000u, 0, 0, 0);
    for (int n = n0 + threadIdx.x; n < n1; n += 256) {
        int s1 = row_start[n + 1];
        for (int s = cursor[n]; s < s1; ++s) csr[s] = sent;
    }
}

// ---------------- p0 = x0 @ P0[0] (layer 0 only) ----------------
__global__ void k_p0(const float* __restrict__ x0, const float* __restrict__ P0l,
                     float* __restrict__ p0, int N) {
    int i = blockIdx.x * blockDim.x + threadIdx.x;
    if (i >= N * 16) return;
    int n = i >> 4, m = i & 15;
    float acc = 0.0f;
    #pragma unroll
    for (int c = 0; c < 16; ++c) acc += x0[n * 16 + c] * P0l[c * 16 + m];
    p0[i] = acc;
}

// ---------------- fused aggregation + node update; KNODE nodes/wave, one drain ----------------
__launch_bounds__(256)
__global__ void k_aggupd(const int* __restrict__ row_start, const uint4* __restrict__ csr,
                         const uint2* __restrict__ tb2, const float* __restrict__ p0g,
                         const float* __restrict__ x0c, const float* __restrict__ x1c,
                         const float* __restrict__ x2c,
                         float* __restrict__ x0n, float* __restrict__ x1n, float* __restrict__ x2n,
                         float* __restrict__ p0out,
                         const float* __restrict__ Wsc, const float* __restrict__ Wa,
                         const float* __restrict__ W1m, const float* __restrict__ W2m,
                         const float* __restrict__ P0n,
                         int N, int ldx12, int wp0) {
    const float INVS = 0.17677669529663687f;  // 1/sqrt(32)
    const float K1  = 1.2909944487358056f;    // sqrt(15)/3
    const float S5H = 1.118033988749895f;     // sqrt(5)/2
    const float K2  = 0.6454972243679028f;    // sqrt(15)/2/3
    __shared__ uint4 ROW[4][KNODE][80];   // 64-edge DMA window + 16-entry prefetch overrun
    __shared__ float XIN[4][KNODE][144];
    __shared__ float AGG[4][144];
    int tid = threadIdx.x;
    int wid = tid >> 6;
    int lane = tid & 63;
    int g = lane >> 4, c = lane & 15;
    int nbase = (blockIdx.x * 4 + wid) * KNODE;

    // row bounds: lane i holds row_start[nbase+i]
    int rsv = 0;
    if (lane <= KNODE) {
        int idx = nbase + lane;
        rsv = row_start[idx < N ? idx : N];
    }

    // ---- prologue: issue ALL staging (4 row-DMAs + x-state -> XIN), then ONE drain ----
    #pragma unroll
    for (int i = 0; i < KNODE; ++i) {
        int e0 = __shfl(rsv, i);
        __builtin_amdgcn_global_load_lds(
            (const __attribute__((address_space(1))) void*)(csr + e0 + lane),
            (__attribute__((address_space(3))) void*)(&ROW[wid][i][0]), 16, 0, 0);
    }
    #pragma unroll
    for (int i = 0; i < KNODE; ++i) {
        int n = nbase + i; if (n > N - 1) n = N - 1;
        float* X = &XIN[wid][i][0];
        if (lane < 16) X[lane] = x0c[(size_t)n * 16 + lane];
        if (ldx12) {
            if (lane < 48) X[16 + lane] = x1c[(size_t)n * 48 + lane];
            X[64 + lane] = x2c[(size_t)n * 80 + lane];
            if (lane < 16) X[128 + lane] = x2c[(size_t)n * 80 + 64 + lane];
        }
    }
    asm volatile("s_waitcnt vmcnt(0)" ::: "memory");

    for (int i = 0; i < KNODE; ++i) {
        int n = nbase + i;
        float a0 = 0, a10 = 0, a11 = 0, a12 = 0, a20 = 0, a21 = 0, a22 = 0, a23 = 0, a24 = 0;
        auto EDGE = [&](uint4 cv, float pv, uint2 Tv) {
            float2 uxy = unp_h2(cv.y);
            float ux = uxy.x, uy = uxy.y, uz = __uint_as_float(cv.z);
            float2 w01 = unp_h2(Tv.x);
            float2 w2_ = unp_h2(Tv.y);
            float sh20 = K1 * (ux * uy);
            float sh21 = K1 * (uy * uz);
            float sh22 = S5H * (uz * uz - 1.0f);
            float sh23 = K1 * (ux * uz);
            float sh24 = K2 * (ux * ux - uy * uy);
            a0 += w01.x * pv;
            float w1p = w01.y * pv, w2p = w2_.x * pv;
            a10 += w1p * ux; a11 += w1p * uy; a12 += w1p * uz;
            a20 += w2p * sh20; a21 += w2p * sh21; a22 += w2p * sh22;
            a23 += w2p * sh23; a24 += w2p * sh24;
        };
        if (n < N) {
            int e0 = __shfl(rsv, i);
            int plen = __shfl(rsv, i + 1) - e0;
            if (plen > 0) {
                const uint4* RB = &ROW[wid][i][0];
                int L = (plen + 3) >> 2;         // padded rows: L even
                int Lm = L < 16 ? L : 16;        // LDS window covers 64 edges
                uint4 c0 = RB[g], c1 = RB[4 + g], c2 = RB[8 + g], c3 = RB[12 + g];
                float p0v = p0g[(c0.x & 0xffffu) * 16 + c]; uint2 T0 = tb2[((c0.x >> 16) & 0xfff0u) | c];
                float p1v = p0g[(c1.x & 0xffffu) * 16 + c]; uint2 T1 = tb2[((c1.x >> 16) & 0xfff0u) | c];
                float p2v = p0g[(c2.x & 0xffffu) * 16 + c]; uint2 T2 = tb2[((c2.x >> 16) & 0xfff0u) | c];
                #pragma unroll 2
                for (int k = 0; k < Lm; ++k) {
                    uint4 c4 = RB[(k + 4) * 4 + g];
                    float p3v = p0g[(c3.x & 0xffffu) * 16 + c];
                    uint2 T3  = tb2[((c3.x >> 16) & 0xfff0u) | c];
                    EDGE(c0, p0v, T0);
                    c0 = c1; c1 = c2; c2 = c3; c3 = c4;
                    p0v = p1v; T0 = T1; p1v = p2v; T1 = T2; p2v = p3v; T2 = T3;
                }
                if (plen > 64) {   // rare fallback beyond LDS window (Poisson(32): ~never)
                    for (int j = e0 + 64 + g; j < e0 + plen; j += 4) {
                        uint4 cx = csr[j];
                        float pv = p0g[(cx.x & 0xffffu) * 16 + c];
                        uint2 Tx = tb2[((cx.x >> 16) & 0xfff0u) | c];
                        EDGE(cx, pv, Tx);
                    }
                }
            }
        }
        #pragma unroll
        for (int m = 16; m < 64; m <<= 1) {
            a0  += __shfl_xor(a0, m);
            a10 += __shfl_xor(a10, m); a11 += __shfl_xor(a11, m); a12 += __shfl_xor(a12, m);
            a20 += __shfl_xor(a20, m); a21 += __shfl_xor(a21, m); a22 += __shfl_xor(a22, m);
            a23 += __shfl_xor(a23, m); a24 += __shfl_xor(a24, m);
        }
        if (n < N) {
            float* A = AGG[wid];
            if (lane < 16) {
                A[c] = a0 * INVS;
                A[16 + c * 3 + 0] = a10 * INVS; A[16 + c * 3 + 1] = a11 * INVS; A[16 + c * 3 + 2] = a12 * INVS;
                A[64 + c * 5 + 0] = a20 * INVS; A[64 + c * 5 + 1] = a21 * INVS; A[64 + c * 5 + 2] = a22 * INVS;
                A[64 + c * 5 + 3] = a23 * INVS; A[64 + c * 5 + 4] = a24 * INVS;
            }
            // wave-synchronous LDS reuse; no barrier needed (wave-private slices)
            const float* X = &XIN[wid][i][0];
            float act = 0.0f;
            if (lane < 48) {
                float sj = 0.0f;
                #pragma unroll
                for (int cc = 0; cc < 16; ++cc)
                    sj += X[cc] * Wsc[cc * 48 + lane] + A[cc] * Wa[cc * 48 + lane];
                float sg = sigmoidf_(sj);
                act = (lane < 16) ? sj * sg : sg;
            }
            if (lane < 16) x0n[(size_t)n * 16 + lane] = act;
            if (wp0) {
                float pn = 0.0f;
                #pragma unroll
                for (int cc = 0; cc < 16; ++cc) pn += __shfl(act, cc) * P0n[cc * 16 + (lane & 15)];
                if (lane < 16) p0out[(size_t)n * 16 + lane] = pn;
            }
            {
                int d = lane >> 4, m = lane & 15;
                float v = 0.0f;
                if (lane < 48) {
                    if (ldx12) {
                        #pragma unroll
                        for (int cc = 0; cc < 16; ++cc) v += X[16 + cc * 3 + d] * W1m[cc * 16 + m];
                    }
                    v += A[16 + m * 3 + d];
                }
                float sg1 = __shfl(act, 16 + m);
                if (lane < 48) x1n[(size_t)n * 48 + m * 3 + d] = v * sg1;
            }
            #pragma unroll
            for (int ch = 0; ch < 2; ++ch) {
                int idx = ch * 64 + lane;
                int d = idx >> 4, m = idx & 15;
                bool on = idx < 80;
                float v = 0.0f;
                if (on) {
                    if (ldx12) {
                        #pragma unroll
                        for (int cc = 0; cc < 16; ++cc) v += X[64 + cc * 5 + d] * W2m[cc * 16 + m];
                    }
                    v += A[64 + m * 5 + d];
                }
                float sg2 = __shfl(act, 32 + (m & 15));
                if (on) x2n[(size_t)n * 80 + m * 5 + d] = v * sg2;
            }
        }
    }
}

// ---------------- final reduction ----------------
__global__ void k_out1(const float* __restrict__ x0, const float* __restrict__ Wout,
                       float* __restrict__ partial, int N) {
    __shared__ float red[256];
    int tid = threadIdx.x;
    float s = 0.0f;
    for (int n = blockIdx.x * blockDim.x + tid; n < N; n += gridDim.x * blockDim.x) {
        float acc = 0.0f;
        #pragma unroll
        for (int cc = 0; cc < 16; ++cc) acc += x0[n * 16 + cc] * Wout[cc];
        s += acc;
    }
    red[tid] = s;
    __syncthreads();
    for (int off = 128; off > 0; off >>= 1) {
        if (tid < off) red[tid] += red[tid + off];
        __syncthreads();
    }
    if (tid == 0) partial[blockIdx.x] = red[0];
}

__global__ void k_out2(const float* __restrict__ partial, float* __restrict__ out,
                       int nb, float scale) {
    __shared__ float red[256];
    int tid = threadIdx.x;
    red[tid] = (tid < nb) ? partial[tid] : 0.0f;
    __syncthreads();
    for (int off = 128; off > 0; off >>= 1) {
        if (tid < off) red[tid] += red[tid + off];
        __syncthreads();
    }
    if (tid == 0) out[0] = red[0] * scale;
}

extern "C" void kernel_launch(void* const* d_in, const int* in_sizes, int n_in,
                              void* d_out, int out_size, void* d_ws, size_t ws_size,
                              hipStream_t stream) {
    const float* pos = (const float*)d_in[0];
    const float* x   = (const float*)d_in[1];
    const int* esrc  = (const int*)d_in[2];
    const int* edst  = (const int*)d_in[3];
    const float* mlp_w1 = (const float*)d_in[5];
    const float* mlp_b1 = (const float*)d_in[6];
    const float* mlp_w2 = (const float*)d_in[7];
    const float* P0  = (const float*)d_in[8];
    const float* Wsc = (const float*)d_in[9];
    const float* Wa  = (const float*)d_in[10];
    const float* W1m = (const float*)d_in[11];
    const float* W2m = (const float*)d_in[12];
    const float* Wout = (const float*)d_in[13];
    int N = in_sizes[0] / 3;
    int E = in_sizes[2];
    int cap = E + 8 * N + 256;
    int nbuck = (N + 127) >> 7;

    char* ws = (char*)d_ws;
    size_t off = 0;
    auto alloc = [&](size_t bytes) -> void* {
        void* p = ws + off;
        off += (bytes + 255) & ~(size_t)255;
        return p;
    };
    int*    cnt       = (int*)alloc((size_t)N * 4);
    int*    row_start = (int*)alloc((size_t)(N + 1) * 4);
    int*    cursor    = (int*)alloc((size_t)N * 4);
    int*    bsum      = (int*)alloc(256 * 4);
    int*    boff      = (int*)alloc(256 * 4);
    int*    bhist     = (int*)alloc(512 * 4);
    int*    bbase     = (int*)alloc(513 * 4);
    int*    bcursor   = (int*)alloc(512 * 4);
    uint4*  csr       = (uint4*)alloc((size_t)cap * 16);
    uint2*  tb2       = (uint2*)alloc((size_t)3 * TSZ2 * 16 * 8);
    float*  p0A = (float*)alloc((size_t)65536 * 16 * 4);   // src is 16-bit
    float*  p0B = (float*)alloc((size_t)65536 * 16 * 4);
    float*  x0A = (float*)alloc((size_t)N * 16 * 4);
    float*  x0B = (float*)alloc((size_t)N * 16 * 4);
    float*  x1B = (float*)alloc((size_t)N * 48 * 4);
    float*  x2B = (float*)alloc((size_t)N * 80 * 4);
    // union region: bbuf (setup-only) aliases x1A + x2A (first written in layer 1)
    size_t x1Asz = ((size_t)N * 48 * 4 + 255) & ~(size_t)255;
    size_t unionSz = x1Asz + (size_t)N * 80 * 4;
    size_t bbufSz = (size_t)E * 16;
    char*  unionA = (char*)alloc(unionSz > bbufSz ? unionSz : bbufSz);
    float* x1A = (float*)unionA;
    float* x2A = (float*)(unionA + x1Asz);
    uint4* bbuf = (uint4*)unionA;
    float*  partial = (float*)alloc(256 * 4);

    int nbscan = (N + SCB - 1) / SCB;
    int nchunk = (E + CHK - 1) / CHK;

    k_table<<<3 * (TSZ2 / 32), 256, 0, stream>>>(mlp_w1, mlp_b1, mlp_w2, tb2, cnt, bhist, N);
    k_hist<<<nchunk, 256, 0, stream>>>(edst, cnt, bhist, E);
    k_scanA<<<nbscan, 256, 0, stream>>>(cnt, bsum, N);
    k_scanB<<<1, 256, 0, stream>>>(bsum, boff, nbscan);
    k_scanC<<<nbscan, 256, 0, stream>>>(cnt, boff, row_start, cursor, N);
    k_bscan<<<1, 512, 0, stream>>>(bhist, bbase, bcursor, nbuck, E);
    k_scat1<<<nchunk, 256, 0, stream>>>(pos, esrc, edst, bcursor, bbuf, E, nbuck);
    k_scat2<<<nbuck, 256, 0, stream>>>(bbuf, bbase, cursor, row_start, csr, N);
    k_p0<<<(N * 16 + 255) / 256, 256, 0, stream>>>(x, P0, p0A, N);

    float* x0bufs[2] = {x0A, x0B};
    float* x1bufs[2] = {x1A, x1B};
    float* x2bufs[2] = {x2A, x2B};
    float* p0bufs[2] = {p0A, p0B};
    int nwave = 4 * KNODE;   // nodes per block
    for (int l = 0; l < 3; ++l) {
        const float* x0c = (l == 0) ? x : x0bufs[l & 1];
        const float* x1c = x1bufs[l & 1];
        const float* x2c = x2bufs[l & 1];
        float* x0n = x0bufs[(l & 1) ^ 1];
        float* x1n = x1bufs[(l & 1) ^ 1];
        float* x2n = x2bufs[(l & 1) ^ 1];
        const float* p0c = p0bufs[l & 1];
        float* p0n = p0bufs[(l & 1) ^ 1];
        const float* P0next = (l < 2) ? (P0 + (l + 1) * 256) : P0;
        k_aggupd<<<(N + nwave - 1) / nwave, 256, 0, stream>>>(
            row_start, csr, tb2 + (size_t)l * TSZ2 * 16, p0c,
            x0c, x1c, x2c, x0n, x1n, x2n, p0n,
            Wsc + l * 768, Wa + l * 768,
            W1m + l * 256, W2m + l * 256, P0next, N,
            (l == 0) ? 0 : 1, (l < 2) ? 1 : 0);
    }
    float scale = (float)(1.0 / sqrt((double)N));
    k_out1<<<256, 256, 0, stream>>>(x0bufs[1], Wout, partial, N);
    k_out2<<<1, 256, 0, stream>>>(partial, (float*)d_out, 256, scale);
}

// Round 11
// 449.826 us; speedup vs baseline: 1.1091x; 1.0074x over previous
//
#include <hip/hip_runtime.h>
#include <hip/hip_fp16.h>
#include <math.h>

#define TSZ2 4096
#define RMAXF 2.0f
#define NBAS 10
#define HID 100
#define SCB 1024   // scan elements per block
#define CHK 4096   // edges per binning block

__device__ __forceinline__ float sigmoidf_(float z) { return 1.0f / (1.0f + __expf(-z)); }
__device__ __forceinline__ float2 unp_h2(unsigned u) {
    __half2 h = __builtin_bit_cast(__half2, u);
    return __half22float2(h);
}
__device__ __forceinline__ unsigned pk_h2(float a, float b) {
    return __builtin_bit_cast(unsigned, __floats2half2_rn(a, b));
}

// ---------------- radial table fused with packing: tb4[l][t][pp] {h2(w0a,w1a),h2(w2a,w0b),h2(w1b,w2b),0}
// also zeroes cnt/bhist (runs before k_hist)
__global__ void k_table(const float* __restrict__ w1, const float* __restrict__ b1,
                        const float* __restrict__ w2, uint4* __restrict__ tb4,
                        int* __restrict__ cnt, int* __restrict__ bhist, int N) {
    int gtid = blockIdx.x * 256 + threadIdx.x;
    for (int i = gtid; i < N; i += gridDim.x * 256) cnt[i] = 0;
    if (gtid < 512) bhist[gtid] = 0;

    int l = blockIdx.x >> 7;
    int t0 = (blockIdx.x & 127) * 32;
    __shared__ float emb[32][NBAS];
    __shared__ float h[32][HID];
    __shared__ float w2s[HID * 48];
    __shared__ float wout[32][48];
    int tid = threadIdx.x;
    for (int i = tid; i < HID * 48; i += 256) w2s[i] = w2[l * HID * 48 + i];
    for (int i = tid; i < 32 * NBAS; i += 256) {
        int tt = i / NBAS, bi = i % NBAS;
        float r = (16.0f * (t0 + tt) + 7.5f) * (RMAXF / 65535.0f);
        float d = (r - (bi + 0.5f) * 0.2f) * 5.0f;
        emb[tt][bi] = (fabsf(d) < 1.0f) ? cosf(1.5707963267948966f * d) * 3.1622776601683795f : 0.0f;
    }
    __syncthreads();
    for (int i = tid; i < 32 * HID; i += 256) {
        int tt = i / HID, hh = i % HID;
        float z = b1[l * HID + hh];
        #pragma unroll
        for (int bi = 0; bi < NBAS; ++bi) z += emb[tt][bi] * w1[(l * NBAS + bi) * HID + hh];
        h[tt][hh] = z * sigmoidf_(z);
    }
    __syncthreads();
    for (int i = tid; i < 32 * 48; i += 256) {
        int tt = i / 48, j = i % 48;
        float o = 0.0f;
        for (int k = 0; k < HID; ++k) o += h[tt][k] * w2s[k * 48 + j];
        wout[tt][j] = o;
    }
    __syncthreads();
    for (int i = tid; i < 32 * 8; i += 256) {
        int tt = i >> 3, pp = i & 7;
        int t = t0 + tt;
        uint4 o = make_uint4(0, 0, 0, 0);
        if (t != TSZ2 - 1) {   // last row stays zero = sentinel
            o.x = pk_h2(wout[tt][2 * pp],      wout[tt][16 + 2 * pp]);
            o.y = pk_h2(wout[tt][32 + 2 * pp], wout[tt][2 * pp + 1]);
            o.z = pk_h2(wout[tt][17 + 2 * pp], wout[tt][33 + 2 * pp]);
        }
        tb4[((size_t)l * TSZ2 + t) * 8 + pp] = o;
    }
}

// ---------------- histogram: per-node (global atomics) + per-bucket (LDS-agg) ----------------
__global__ void k_hist(const int* __restrict__ edst, int* cnt, int* bhist, int E) {
    __shared__ int lb[512];
    int tid = threadIdx.x;
    for (int i = tid; i < 512; i += 256) lb[i] = 0;
    __syncthreads();
    int e0 = blockIdx.x * CHK;
    #pragma unroll
    for (int k = 0; k < CHK / 256; ++k) {
        int e = e0 + k * 256 + tid;
        if (e < E) {
            int d = edst[e];
            atomicAdd(&cnt[d], 1);
            atomicAdd(&lb[d >> 7], 1);
        }
    }
    __syncthreads();
    for (int i = tid; i < 512; i += 256) if (lb[i]) atomicAdd(&bhist[i], lb[i]);
}

// ---------------- bucket scan (1 block, 512 threads) ----------------
__global__ void k_bscan(const int* __restrict__ bhist, int* __restrict__ bbase,
                        int* __restrict__ bcursor, int nbuck, int E) {
    __shared__ int part[512];
    int t = threadIdx.x;
    part[t] = (t < nbuck) ? bhist[t] : 0;
    __syncthreads();
    for (int off = 1; off < 512; off <<= 1) {
        int v = (t >= off) ? part[t - off] : 0;
        __syncthreads();
        part[t] += v;
        __syncthreads();
    }
    int ex = (t == 0) ? 0 : part[t - 1];
    if (t < nbuck) { bbase[t] = ex; bcursor[t] = ex; }
    if (t == 0) bbase[nbuck] = E;
}

// ---------------- node-level scans (padded to 8) ----------------
__global__ void k_scanA(const int* __restrict__ cnt, int* __restrict__ bsum, int N) {
    __shared__ int red[256];
    int base = blockIdx.x * SCB;
    int t = threadIdx.x;
    int s = 0;
    #pragma unroll
    for (int k = 0; k < 4; ++k) {
        int i = base + k * 256 + t;
        if (i < N) s += (cnt[i] + 7) & ~7;
    }
    red[t] = s;
    __syncthreads();
    for (int off = 128; off > 0; off >>= 1) {
        if (t < off) red[t] += red[t + off];
        __syncthreads();
    }
    if (t == 0) bsum[blockIdx.x] = red[0];
}

__global__ void k_scanB(const int* __restrict__ bsum, int* __restrict__ boff, int nb) {
    __shared__ int part[256];
    int t = threadIdx.x;
    part[t] = (t < nb) ? bsum[t] : 0;
    __syncthreads();
    for (int off = 1; off < 256; off <<= 1) {
        int v = (t >= off) ? part[t - off] : 0;
        __syncthreads();
        part[t] += v;
        __syncthreads();
    }
    boff[t] = (t == 0) ? 0 : part[t - 1];
}

__global__ void k_scanC(const int* __restrict__ cnt, const int* __restrict__ boff,
                        int* __restrict__ row_start, int* __restrict__ cursor, int N) {
    __shared__ int part[256];
    int b = blockIdx.x, t = threadIdx.x;
    int base = b * SCB;
    int v[4];
    int s = 0;
    #pragma unroll
    for (int k = 0; k < 4; ++k) {
        int i = base + t * 4 + k;
        v[k] = (i < N) ? ((cnt[i] + 7) & ~7) : 0;
        s += v[k];
    }
    part[t] = s;
    __syncthreads();
    for (int off = 1; off < 256; off <<= 1) {
        int x = (t >= off) ? part[t - off] : 0;
        __syncthreads();
        part[t] += x;
        __syncthreads();
    }
    int run = boff[b] + ((t == 0) ? 0 : part[t - 1]);
    #pragma unroll
    for (int k = 0; k < 4; ++k) {
        int i = base + t * 4 + k;
        if (i < N) {
            row_start[i] = run; cursor[i] = run; run += v[k];
            if (i == N - 1) row_start[N] = run;
        }
    }
}

// ---------------- phase 1: bin edges into dst-buckets with geometry, burst writes ----------------
__global__ void k_scat1(const float* __restrict__ pos, const int* __restrict__ esrc,
                        const int* __restrict__ edst, int* __restrict__ bcursor,
                        uint4* __restrict__ bbuf, int E, int nbuck) {
    __shared__ int lcnt[512];
    __shared__ int base[512];
    int tid = threadIdx.x;
    for (int i = tid; i < 512; i += 256) lcnt[i] = 0;
    __syncthreads();
    int e0 = blockIdx.x * CHK;
    #pragma unroll
    for (int k = 0; k < CHK / 256; ++k) {
        int e = e0 + k * 256 + tid;
        if (e < E) atomicAdd(&lcnt[edst[e] >> 7], 1);
    }
    __syncthreads();
    for (int b = tid; b < nbuck; b += 256)
        base[b] = lcnt[b] ? atomicAdd(&bcursor[b], lcnt[b]) : 0;
    __syncthreads();
    #pragma unroll
    for (int k = 0; k < CHK / 256; ++k) {
        int e = e0 + k * 256 + tid;
        if (e >= E) continue;
        int s = esrc[e], d = edst[e];
        float vx = pos[s * 3 + 0] - pos[d * 3 + 0];
        float vy = pos[s * 3 + 1] - pos[d * 3 + 1];
        float vz = pos[s * 3 + 2] - pos[d * 3 + 2];
        float r = sqrtf(vx * vx + vy * vy + vz * vz);
        float kf = 1.7320508075688772f / (r + 1e-12f);   // sqrt(3)/r premult
        unsigned rtfix = (unsigned)fminf(r * (65535.0f / RMAXF) + 0.5f, 65535.0f);
        uint4 o;
        o.x = (unsigned)s | (rtfix << 16);
        o.y = pk_h2(vx * kf, vy * kf);
        o.z = __float_as_uint(vz * kf);
        o.w = (unsigned)d;
        int slot = atomicAdd(&base[d >> 7], 1);
        bbuf[slot] = o;
    }
}

// ---------------- phase 2: bucket -> exact CSR slot + sentinel padfill (fused) ----------------
__global__ void k_scat2(const uint4* __restrict__ bbuf, const int* __restrict__ bbase,
                        int* __restrict__ cursor, const int* __restrict__ row_start,
                        uint4* __restrict__ csr, int N) {
    int b = blockIdx.x;
    int j0 = bbase[b], j1 = bbase[b + 1];
    for (int j = j0 + threadIdx.x; j < j1; j += 256) {
        uint4 e = bbuf[j];
        int d = (int)e.w;
        int slot = atomicAdd(&cursor[d], 1);
        csr[slot] = e;
    }
    __syncthreads();
    int n0 = b << 7, n1 = min(n0 + 128, N);
    uint4 sent = make_uint4(0xFFFF0000u, 0, 0, 0);
    for (int n = n0 + threadIdx.x; n < n1; n += 256) {
        int s1 = row_start[n + 1];
        for (int s = cursor[n]; s < s1; ++s) csr[s] = sent;
    }
}

// ---------------- p0 = x0 @ P0[0] (layer 0 only) ----------------
__global__ void k_p0(const float* __restrict__ x0, const float* __restrict__ P0l,
                     float* __restrict__ p0, int N) {
    int i = blockIdx.x * blockDim.x + threadIdx.x;
    if (i >= N * 16) return;
    int n = i >> 4, m = i & 15;
    float acc = 0.0f;
    #pragma unroll
    for (int c = 0; c < 16; ++c) acc += x0[n * 16 + c] * P0l[c * 16 + m];
    p0[i] = acc;
}

// ---------------- fused aggregation + node update; wave/node, 8 edge-slots x 8 ch-pairs, LDS row ----------------
__launch_bounds__(256)
__global__ void k_aggupd(const int* __restrict__ row_start, const uint4* __restrict__ csr,
                         const uint4* __restrict__ tb4, const float* __restrict__ p0g,
                         const float* __restrict__ x0c, const float* __restrict__ x1c,
                         const float* __restrict__ x2c,
                         float* __restrict__ x0n, float* __restrict__ x1n, float* __restrict__ x2n,
                         float* __restrict__ p0out,
                         const float* __restrict__ Wsc, const float* __restrict__ Wa,
                         const float* __restrict__ W1m, const float* __restrict__ W2m,
                         const float* __restrict__ P0n,
                         int N, int ldx12, int wp0) {
    const float INVS = 0.17677669529663687f;  // 1/sqrt(32)
    const float K1  = 1.2909944487358056f;    // sqrt(15)/3  (u premult by sqrt3)
    const float S5H = 1.118033988749895f;     // sqrt(5)/2
    const float K2  = 0.6454972243679028f;    // sqrt(15)/2/3
    __shared__ uint4 ROW[4][96];   // 64-edge DMA window + 32-slot prefetch overrun
    __shared__ float AGG[4][144];
    __shared__ float XIN[4][144];
    int tid = threadIdx.x;
    int wid = tid >> 6;
    int lane = tid & 63;
    int n = blockIdx.x * 4 + wid;
    int g = lane >> 3, p = lane & 7;    // edge slot (8), channel pair (8)
    float A0[2] = {0, 0};
    float A1[2][3] = {};
    float A2[2][5] = {};
    float xr0 = 0, xr1 = 0, xr2 = 0, xr2b = 0;
    auto EDGE = [&](uint4 cv, float2 Pv, uint4 Tv) {
        float2 uxy = unp_h2(cv.y);
        float ux = uxy.x, uy = uxy.y, uz = __uint_as_float(cv.z);
        float sh20 = K1 * (ux * uy);
        float sh21 = K1 * (uy * uz);
        float sh22 = S5H * (uz * uz - 1.0f) * (1.0f / 3.0f) * 3.0f; // uz premult sqrt3: (uz^2-1)->(uz_s^2-3)/3
        sh22 = S5H * ((uz * uz) * (1.0f / 3.0f) - 1.0f) * 3.0f * (1.0f / 3.0f); // overwritten below
        sh22 = S5H * (uz * uz - 3.0f) * (1.0f / 3.0f); // correct: u premult sqrt3 -> uz^2 = 3*uzr^2
        float sh23 = K1 * (ux * uz);
        float sh24 = K2 * (ux * ux - uy * uy);
        float2 q0 = unp_h2(Tv.x);   // w0a, w1a
        float2 q1 = unp_h2(Tv.y);   // w2a, w0b
        float2 q2 = unp_h2(Tv.z);   // w1b, w2b
        A0[0] += q0.x * Pv.x;
        float w1a = q0.y * Pv.x, w2a = q1.x * Pv.x;
        A1[0][0] += w1a * ux; A1[0][1] += w1a * uy; A1[0][2] += w1a * uz;
        A2[0][0] += w2a * sh20; A2[0][1] += w2a * sh21; A2[0][2] += w2a * sh22;
        A2[0][3] += w2a * sh23; A2[0][4] += w2a * sh24;
        A0[1] += q1.y * Pv.y;
        float w1b = q2.x * Pv.y, w2b = q2.y * Pv.y;
        A1[1][0] += w1b * ux; A1[1][1] += w1b * uy; A1[1][2] += w1b * uz;
        A2[1][0] += w2b * sh20; A2[1][1] += w2b * sh21; A2[1][2] += w2b * sh22;
        A2[1][3] += w2b * sh23; A2[1][4] += w2b * sh24;
    };
    if (n < N) {
        int e0 = row_start[n], e1 = row_start[n + 1];
        int plen = e1 - e0;
        if (lane < 16) xr0 = x0c[(size_t)n * 16 + lane];
        if (ldx12) {
            if (lane < 48) xr1 = x1c[(size_t)n * 48 + lane];
            xr2 = x2c[(size_t)n * 80 + lane];
            if (lane < 16) xr2b = x2c[(size_t)n * 80 + 64 + lane];
        }
        if (plen > 0) {
            __builtin_amdgcn_global_load_lds(
                (const __attribute__((address_space(1))) void*)(csr + e0 + lane),
                (__attribute__((address_space(3))) void*)(&ROW[wid][0]), 16, 0, 0);
            asm volatile("s_waitcnt vmcnt(0)" ::: "memory");
            const uint4* RB = &ROW[wid][0];
            const float2* p0f2 = (const float2*)p0g;
            int L = (plen + 7) >> 3;          // 8-edge groups (padded rows: exact)
            int Lm = L < 8 ? L : 8;           // LDS window covers 64 edges
            uint4 ca = RB[g];
            uint4 cb = RB[8 + g];
            uint4 cc_ = RB[16 + g];
            float2 Pa = p0f2[(ca.x & 0xffffu) * 8 + p];
            uint4  Ta = tb4[(ca.x >> 20) * 8 + p];
            float2 Pb = p0f2[(cb.x & 0xffffu) * 8 + p];
            uint4  Tb = tb4[(cb.x >> 20) * 8 + p];
            for (int k = 0; k < Lm; ++k) {
                uint4 cn = RB[(k + 3) * 8 + g];
                float2 Pc = p0f2[(cc_.x & 0xffffu) * 8 + p];
                uint4  Tc = tb4[(cc_.x >> 20) * 8 + p];
                EDGE(ca, Pa, Ta);
                ca = cb; Pa = Pb; Ta = Tb;
                cb = cc_; Pb = Pc; Tb = Tc;
                cc_ = cn;
            }
            if (plen > 64) {   // rare fallback beyond LDS window (Poisson(32): ~never)
                for (int j = e0 + 64 + g; j < e1; j += 8) {
                    uint4 cx = csr[j];
                    float2 Pv = p0f2[(cx.x & 0xffffu) * 8 + p];
                    uint4  Tv = tb4[(cx.x >> 20) * 8 + p];
                    EDGE(cx, Pv, Tv);
                }
            }
        }
    }
    // butterfly over g (lane bits 3,4,5)
    #pragma unroll
    for (int m = 8; m < 64; m <<= 1) {
        #pragma unroll
        for (int a = 0; a < 2; ++a) {
            A0[a] += __shfl_xor(A0[a], m);
            #pragma unroll
            for (int d = 0; d < 3; ++d) A1[a][d] += __shfl_xor(A1[a][d], m);
            #pragma unroll
            for (int d = 0; d < 5; ++d) A2[a][d] += __shfl_xor(A2[a][d], m);
        }
    }
    {
        float* Ag = AGG[wid];
        if (g < 2) {
            int a = g;               // g==0 -> channel 2p, g==1 -> channel 2p+1
            int c = 2 * p + a;
            Ag[c] = A0[a] * INVS;
            #pragma unroll
            for (int d = 0; d < 3; ++d) Ag[16 + c * 3 + d] = A1[a][d] * INVS;
            #pragma unroll
            for (int d = 0; d < 5; ++d) Ag[64 + c * 5 + d] = A2[a][d] * INVS;
        }
        float* X = XIN[wid];
        if (lane < 16) X[lane] = xr0;
        if (lane < 48) X[16 + lane] = xr1;
        X[64 + lane] = xr2;
        if (lane < 16) X[128 + lane] = xr2b;
    }
    __syncthreads();
    if (n >= N) return;
    const float* X = XIN[wid];
    const float* A = AGG[wid];
    float act = 0.0f;
    if (lane < 48) {
        float sj = 0.0f;
        #pragma unroll
        for (int cc = 0; cc < 16; ++cc)
            sj += X[cc] * Wsc[cc * 48 + lane] + A[cc] * Wa[cc * 48 + lane];
        float sg = sigmoidf_(sj);
        act = (lane < 16) ? sj * sg : sg;
    }
    if (lane < 16) x0n[(size_t)n * 16 + lane] = act;
    if (wp0) {
        float pn = 0.0f;
        #pragma unroll
        for (int cc = 0; cc < 16; ++cc) pn += __shfl(act, cc) * P0n[cc * 16 + (lane & 15)];
        if (lane < 16) p0out[(size_t)n * 16 + lane] = pn;
    }
    {
        int d = lane >> 4, m = lane & 15;
        float v = 0.0f;
        if (lane < 48) {
            if (ldx12) {
                #pragma unroll
                for (int cc = 0; cc < 16; ++cc) v += X[16 + cc * 3 + d] * W1m[cc * 16 + m];
            }
            v += A[16 + m * 3 + d];
        }
        float sg1 = __shfl(act, 16 + m);
        if (lane < 48) x1n[(size_t)n * 48 + m * 3 + d] = v * sg1;
    }
    #pragma unroll
    for (int ch = 0; ch < 2; ++ch) {
        int idx = ch * 64 + lane;
        int d = idx >> 4, m = idx & 15;
        bool on = idx < 80;
        float v = 0.0f;
        if (on) {
            if (ldx12) {
                #pragma unroll
                for (int cc = 0; cc < 16; ++cc) v += X[64 + cc * 5 + d] * W2m[cc * 16 + m];
            }
            v += A[64 + m * 5 + d];
        }
        float sg2 = __shfl(act, 32 + (m & 15));
        if (on) x2n[(size_t)n * 80 + m * 5 + d] = v * sg2;
    }
}

// ---------------- final reduction ----------------
__global__ void k_out1(const float* __restrict__ x0, const float* __restrict__ Wout,
                       float* __restrict__ partial, int N) {
    __shared__ float red[256];
    int tid = threadIdx.x;
    float s = 0.0f;
    for (int n = blockIdx.x * blockDim.x + tid; n < N; n += gridDim.x * blockDim.x) {
        float acc = 0.0f;
        #pragma unroll
        for (int cc = 0; cc < 16; ++cc) acc += x0[n * 16 + cc] * Wout[cc];
        s += acc;
    }
    red[tid] = s;
    __syncthreads();
    for (int off = 128; off > 0; off >>= 1) {
        if (tid < off) red[tid] += red[tid + off];
        __syncthreads();
    }
    if (tid == 0) partial[blockIdx.x] = red[0];
}

__global__ void k_out2(const float* __restrict__ partial, float* __restrict__ out,
                       int nb, float scale) {
    __shared__ float red[256];
    int tid = threadIdx.x;
    red[tid] = (tid < nb) ? partial[tid] : 0.0f;
    __syncthreads();
    for (int off = 128; off > 0; off >>= 1) {
        if (tid < off) red[tid] += red[tid + off];
        __syncthreads();
    }
    if (tid == 0) out[0] = red[0] * scale;
}

extern "C" void kernel_launch(void* const* d_in, const int* in_sizes, int n_in,
                              void* d_out, int out_size, void* d_ws, size_t ws_size,
                              hipStream_t stream) {
    const float* pos = (const float*)d_in[0];
    const float* x   = (const float*)d_in[1];
    const int* esrc  = (const int*)d_in[2];
    const int* edst  = (const int*)d_in[3];
    const float* mlp_w1 = (const float*)d_in[5];
    const float* mlp_b1 = (const float*)d_in[6];
    const float* mlp_w2 = (const float*)d_in[7];
    const float* P0  = (const float*)d_in[8];
    const float* Wsc = (const float*)d_in[9];
    const float* Wa  = (const float*)d_in[10];
    const float* W1m = (const float*)d_in[11];
    const float* W2m = (const float*)d_in[12];
    const float* Wout = (const float*)d_in[13];
    int N = in_sizes[0] / 3;
    int E = in_sizes[2];
    int cap = E + 8 * N + 256;
    int nbuck = (N + 127) >> 7;

    char* ws = (char*)d_ws;
    size_t off = 0;
    auto alloc = [&](size_t bytes) -> void* {
        void* p = ws + off;
        off += (bytes + 255) & ~(size_t)255;
        return p;
    };
    int*    cnt       = (int*)alloc((size_t)N * 4);
    int*    row_start = (int*)alloc((size_t)(N + 1) * 4);
    int*    cursor    = (int*)alloc((size_t)N * 4);
    int*    bsum      = (int*)alloc(256 * 4);
    int*    boff      = (int*)alloc(256 * 4);
    int*    bhist     = (int*)alloc(512 * 4);
    int*    bbase     = (int*)alloc(513 * 4);
    int*    bcursor   = (int*)alloc(512 * 4);
    uint4*  csr       = (uint4*)alloc((size_t)cap * 16);
    uint4*  tb4       = (uint4*)alloc((size_t)3 * TSZ2 * 8 * 16);
    float*  p0A = (float*)alloc((size_t)65536 * 16 * 4);   // src is 16-bit
    float*  p0B = (float*)alloc((size_t)65536 * 16 * 4);
    float*  x0A = (float*)alloc((size_t)N * 16 * 4);
    float*  x0B = (float*)alloc((size_t)N * 16 * 4);
    float*  x1B = (float*)alloc((size_t)N * 48 * 4);
    float*  x2B = (float*)alloc((size_t)N * 80 * 4);
    // union region: bbuf (setup-only) aliases x1A + x2A (first written in layer 1)
    size_t x1Asz = ((size_t)N * 48 * 4 + 255) & ~(size_t)255;
    size_t unionSz = x1Asz + (size_t)N * 80 * 4;
    size_t bbufSz = (size_t)E * 16;
    char*  unionA = (char*)alloc(unionSz > bbufSz ? unionSz : bbufSz);
    float* x1A = (float*)unionA;
    float* x2A = (float*)(unionA + x1Asz);
    uint4* bbuf = (uint4*)unionA;
    float*  partial = (float*)alloc(256 * 4);

    int nbscan = (N + SCB - 1) / SCB;
    int nchunk = (E + CHK - 1) / CHK;

    k_table<<<3 * (TSZ2 / 32), 256, 0, stream>>>(mlp_w1, mlp_b1, mlp_w2, tb4, cnt, bhist, N);
    k_hist<<<nchunk, 256, 0, stream>>>(edst, cnt, bhist, E);
    k_scanA<<<nbscan, 256, 0, stream>>>(cnt, bsum, N);
    k_scanB<<<1, 256, 0, stream>>>(bsum, boff, nbscan);
    k_scanC<<<nbscan, 256, 0, stream>>>(cnt, boff, row_start, cursor, N);
    k_bscan<<<1, 512, 0, stream>>>(bhist, bbase, bcursor, nbuck, E);
    k_scat1<<<nchunk, 256, 0, stream>>>(pos, esrc, edst, bcursor, bbuf, E, nbuck);
    k_scat2<<<nbuck, 256, 0, stream>>>(bbuf, bbase, cursor, row_start, csr, N);
    k_p0<<<(N * 16 + 255) / 256, 256, 0, stream>>>(x, P0, p0A, N);

    float* x0bufs[2] = {x0A, x0B};
    float* x1bufs[2] = {x1A, x1B};
    float* x2bufs[2] = {x2A, x2B};
    float* p0bufs[2] = {p0A, p0B};
    for (int l = 0; l < 3; ++l) {
        const float* x0c = (l == 0) ? x : x0bufs[l & 1];
        const float* x1c = x1bufs[l & 1];
        const float* x2c = x2bufs[l & 1];
        float* x0n = x0bufs[(l & 1) ^ 1];
        float* x1n = x1bufs[(l & 1) ^ 1];
        float* x2n = x2bufs[(l & 1) ^ 1];
        const float* p0c = p0bufs[l & 1];
        float* p0n = p0bufs[(l & 1) ^ 1];
        const float* P0next = (l < 2) ? (P0 + (l + 1) * 256) : P0;
        k_aggupd<<<(N + 3) / 4, 256, 0, stream>>>(
            row_start, csr, tb4 + (size_t)l * TSZ2 * 8, p0c,
            x0c, x1c, x2c, x0n, x1n, x2n, p0n,
            Wsc + l * 768, Wa + l * 768,
            W1m + l * 256, W2m + l * 256, P0next, N,
            (l == 0) ? 0 : 1, (l < 2) ? 1 : 0);
    }
    float scale = (float)(1.0 / sqrt((double)N));
    k_out1<<<256, 256, 0, stream>>>(x0bufs[1], Wout, partial, N);
    k_out2<<<1, 256, 0, stream>>>(partial, (float*)d_out, 256, scale);
}

// Round 12
// 381.241 us; speedup vs baseline: 1.3086x; 1.1799x over previous
//
#include <hip/hip_runtime.h>
#include <hip/hip_fp16.h>
#include <math.h>

#define TSZ2 4096
#define RMAXF 2.0f
#define NBAS 10
#define HID 100
#define SCB 1024   // scan elements per block
#define CHK 4096   // edges per binning block

__device__ __forceinline__ float sigmoidf_(float z) { return 1.0f / (1.0f + __expf(-z)); }
__device__ __forceinline__ float2 unp_h2(unsigned u) {
    __half2 h = __builtin_bit_cast(__half2, u);
    return __half22float2(h);
}
__device__ __forceinline__ unsigned pk_h2(float a, float b) {
    return __builtin_bit_cast(unsigned, __floats2half2_rn(a, b));
}

// ---------------- radial table fused with packing: tb2[l][t][c] {h2(w0,w1), h2(w2,0)} ----------------
// also zeroes cnt/bhist (runs before k_hist)
__global__ void k_table(const float* __restrict__ w1, const float* __restrict__ b1,
                        const float* __restrict__ w2, uint2* __restrict__ tb2,
                        int* __restrict__ cnt, int* __restrict__ bhist, int N) {
    int gtid = blockIdx.x * 256 + threadIdx.x;
    for (int i = gtid; i < N; i += gridDim.x * 256) cnt[i] = 0;
    if (gtid < 512) bhist[gtid] = 0;

    int l = blockIdx.x >> 7;
    int t0 = (blockIdx.x & 127) * 32;
    __shared__ float emb[32][NBAS];
    __shared__ float h[32][HID];
    __shared__ float w2s[HID * 48];
    __shared__ float wout[32][48];
    int tid = threadIdx.x;
    for (int i = tid; i < HID * 48; i += 256) w2s[i] = w2[l * HID * 48 + i];
    for (int i = tid; i < 32 * NBAS; i += 256) {
        int tt = i / NBAS, bi = i % NBAS;
        float r = (16.0f * (t0 + tt) + 7.5f) * (RMAXF / 65535.0f);
        float d = (r - (bi + 0.5f) * 0.2f) * 5.0f;
        emb[tt][bi] = (fabsf(d) < 1.0f) ? cosf(1.5707963267948966f * d) * 3.1622776601683795f : 0.0f;
    }
    __syncthreads();
    for (int i = tid; i < 32 * HID; i += 256) {
        int tt = i / HID, hh = i % HID;
        float z = b1[l * HID + hh];
        #pragma unroll
        for (int bi = 0; bi < NBAS; ++bi) z += emb[tt][bi] * w1[(l * NBAS + bi) * HID + hh];
        h[tt][hh] = z * sigmoidf_(z);
    }
    __syncthreads();
    for (int i = tid; i < 32 * 48; i += 256) {
        int tt = i / 48, j = i % 48;
        float o = 0.0f;
        for (int k = 0; k < HID; ++k) o += h[tt][k] * w2s[k * 48 + j];
        wout[tt][j] = o;
    }
    __syncthreads();
    for (int i = tid; i < 32 * 16; i += 256) {
        int tt = i >> 4, c = i & 15;
        int t = t0 + tt;
        uint2 o = make_uint2(0, 0);
        if (t != TSZ2 - 1) {   // last row stays zero = sentinel
            o.x = pk_h2(wout[tt][c], wout[tt][16 + c]);
            o.y = pk_h2(wout[tt][32 + c], 0.0f);
        }
        tb2[((size_t)l * TSZ2 + t) * 16 + c] = o;
    }
}

// ---------------- histogram + fused p0 (layer 0) ----------------
__global__ void k_hist(const int* __restrict__ edst, int* cnt, int* bhist, int E,
                       const float* __restrict__ x0, const float* __restrict__ P0l,
                       float* __restrict__ p0, int N) {
    __shared__ int lb[512];
    int tid = threadIdx.x;
    for (int i = tid; i < 512; i += 256) lb[i] = 0;
    __syncthreads();
    int e0 = blockIdx.x * CHK;
    #pragma unroll
    for (int k = 0; k < CHK / 256; ++k) {
        int e = e0 + k * 256 + tid;
        if (e < E) {
            int d = edst[e];
            atomicAdd(&cnt[d], 1);
            atomicAdd(&lb[d >> 7], 1);
        }
    }
    // fused p0 = x0 @ P0[0] (independent work; hides under atomic latency)
    for (int i = blockIdx.x * 256 + tid; i < N * 16; i += gridDim.x * 256) {
        int n = i >> 4, m = i & 15;
        float acc = 0.0f;
        #pragma unroll
        for (int c = 0; c < 16; ++c) acc += x0[n * 16 + c] * P0l[c * 16 + m];
        p0[i] = acc;
    }
    __syncthreads();
    for (int i = tid; i < 512; i += 256) if (lb[i]) atomicAdd(&bhist[i], lb[i]);
}

// ---------------- node-level scan A: per-block sums (padded to 8) ----------------
__global__ void k_scanA(const int* __restrict__ cnt, int* __restrict__ bsum, int N) {
    __shared__ int red[256];
    int base = blockIdx.x * SCB;
    int t = threadIdx.x;
    int s = 0;
    #pragma unroll
    for (int k = 0; k < 4; ++k) {
        int i = base + k * 256 + t;
        if (i < N) s += (cnt[i] + 7) & ~7;
    }
    red[t] = s;
    __syncthreads();
    for (int off = 128; off > 0; off >>= 1) {
        if (t < off) red[t] += red[t + off];
        __syncthreads();
    }
    if (t == 0) bsum[blockIdx.x] = red[0];
}

// ---------------- merged: block 0 = scan of bsum, block 1 = bucket scan ----------------
__global__ void k_scans(const int* __restrict__ bsum, int* __restrict__ boff, int nbscan,
                        const int* __restrict__ bhist, int* __restrict__ bbase,
                        int* __restrict__ bcursor, int nbuck, int E) {
    __shared__ int part[512];
    int t = threadIdx.x;
    if (blockIdx.x == 0) {
        part[t] = (t < nbscan) ? bsum[t] : 0;
        __syncthreads();
        for (int off = 1; off < 512; off <<= 1) {
            int v = (t >= off) ? part[t - off] : 0;
            __syncthreads();
            part[t] += v;
            __syncthreads();
        }
        if (t < 256) boff[t] = (t == 0) ? 0 : part[t - 1];
    } else {
        part[t] = (t < nbuck) ? bhist[t] : 0;
        __syncthreads();
        for (int off = 1; off < 512; off <<= 1) {
            int v = (t >= off) ? part[t - off] : 0;
            __syncthreads();
            part[t] += v;
            __syncthreads();
        }
        int ex = (t == 0) ? 0 : part[t - 1];
        if (t < nbuck) { bbase[t] = ex; bcursor[t] = ex; }
        if (t == 0) bbase[nbuck] = E;
    }
}

__global__ void k_scanC(const int* __restrict__ cnt, const int* __restrict__ boff,
                        int* __restrict__ row_start, int* __restrict__ cursor, int N) {
    __shared__ int part[256];
    int b = blockIdx.x, t = threadIdx.x;
    int base = b * SCB;
    int v[4];
    int s = 0;
    #pragma unroll
    for (int k = 0; k < 4; ++k) {
        int i = base + t * 4 + k;
        v[k] = (i < N) ? ((cnt[i] + 7) & ~7) : 0;
        s += v[k];
    }
    part[t] = s;
    __syncthreads();
    for (int off = 1; off < 256; off <<= 1) {
        int x = (t >= off) ? part[t - off] : 0;
        __syncthreads();
        part[t] += x;
        __syncthreads();
    }
    int run = boff[b] + ((t == 0) ? 0 : part[t - 1]);
    #pragma unroll
    for (int k = 0; k < 4; ++k) {
        int i = base + t * 4 + k;
        if (i < N) {
            row_start[i] = run; cursor[i] = run; run += v[k];
            if (i == N - 1) row_start[N] = run;
        }
    }
}

// ---------------- phase 1: bin edges into dst-buckets with geometry, burst writes ----------------
__global__ void k_scat1(const float* __restrict__ pos, const int* __restrict__ esrc,
                        const int* __restrict__ edst, int* __restrict__ bcursor,
                        uint4* __restrict__ bbuf, int E, int nbuck) {
    __shared__ int lcnt[512];
    __shared__ int base[512];
    int tid = threadIdx.x;
    for (int i = tid; i < 512; i += 256) lcnt[i] = 0;
    __syncthreads();
    int e0 = blockIdx.x * CHK;
    #pragma unroll
    for (int k = 0; k < CHK / 256; ++k) {
        int e = e0 + k * 256 + tid;
        if (e < E) atomicAdd(&lcnt[edst[e] >> 7], 1);
    }
    __syncthreads();
    for (int b = tid; b < nbuck; b += 256)
        base[b] = lcnt[b] ? atomicAdd(&bcursor[b], lcnt[b]) : 0;
    __syncthreads();
    #pragma unroll
    for (int k = 0; k < CHK / 256; ++k) {
        int e = e0 + k * 256 + tid;
        if (e >= E) continue;
        int s = esrc[e], d = edst[e];
        float vx = pos[s * 3 + 0] - pos[d * 3 + 0];
        float vy = pos[s * 3 + 1] - pos[d * 3 + 1];
        float vz = pos[s * 3 + 2] - pos[d * 3 + 2];
        float r = sqrtf(vx * vx + vy * vy + vz * vz);
        float kf = 1.7320508075688772f / (r + 1e-12f);   // sqrt(3)/r premult
        unsigned rtfix = (unsigned)fminf(r * (65535.0f / RMAXF) + 0.5f, 65535.0f);
        uint4 o;
        o.x = (unsigned)s | (rtfix << 16);
        o.y = pk_h2(vx * kf, vy * kf);
        o.z = __float_as_uint(vz * kf);
        o.w = (unsigned)d;
        int slot = atomicAdd(&base[d >> 7], 1);
        bbuf[slot] = o;
    }
}

// ---------------- phase 2: bucket -> exact CSR slot + sentinel padfill (fused) ----------------
__global__ void k_scat2(const uint4* __restrict__ bbuf, const int* __restrict__ bbase,
                        int* __restrict__ cursor, const int* __restrict__ row_start,
                        uint4* __restrict__ csr, int N) {
    int b = blockIdx.x;
    int j0 = bbase[b], j1 = bbase[b + 1];
    for (int j = j0 + threadIdx.x; j < j1; j += 256) {
        uint4 e = bbuf[j];
        int d = (int)e.w;
        int slot = atomicAdd(&cursor[d], 1);
        csr[slot] = e;
    }
    __syncthreads();
    int n0 = b << 7, n1 = min(n0 + 128, N);
    uint4 sent = make_uint4(0xFFFF0000u, 0, 0, 0);
    for (int n = n0 + threadIdx.x; n < n1; n += 256) {
        int s1 = row_start[n + 1];
        for (int s = cursor[n]; s < s1; ++s) csr[s] = sent;
    }
}

// ---------------- fused aggregation + node update; wave per node (r8 structure), fp16 x1/x2 ----------------
__launch_bounds__(256)
__global__ void k_aggupd(const int* __restrict__ row_start, const uint4* __restrict__ csr,
                         const uint2* __restrict__ tb2, const float* __restrict__ p0g,
                         const float* __restrict__ x0c, const __half* __restrict__ x1c,
                         const __half* __restrict__ x2c,
                         float* __restrict__ x0n, __half* __restrict__ x1n, __half* __restrict__ x2n,
                         float* __restrict__ p0out,
                         const float* __restrict__ Wsc, const float* __restrict__ Wa,
                         const float* __restrict__ W1m, const float* __restrict__ W2m,
                         const float* __restrict__ P0n,
                         int N, int ldx12, int wp0) {
    const float INVS = 0.17677669529663687f;  // 1/sqrt(32)
    const float K1  = 1.2909944487358056f;    // sqrt(15)/3
    const float S5H = 1.118033988749895f;     // sqrt(5)/2
    const float K2  = 0.6454972243679028f;    // sqrt(15)/2/3
    __shared__ uint4 ROW[4][144];   // per-wave CSR row buffer (128 edges + overrun slack)
    __shared__ float AGG[4][144];
    __shared__ float XIN[4][144];
    int tid = threadIdx.x;
    int wid = tid >> 6;
    int lane = tid & 63;
    int n = blockIdx.x * 4 + wid;
    int g = lane >> 4, c = lane & 15;
    float a0 = 0, a10 = 0, a11 = 0, a12 = 0, a20 = 0, a21 = 0, a22 = 0, a23 = 0, a24 = 0;
    float xr0 = 0, xr1 = 0, xr2 = 0, xr2b = 0;
    auto EDGE = [&](uint4 cv, float pv, uint2 Tv) {
        float2 uxy = unp_h2(cv.y);
        float ux = uxy.x, uy = uxy.y, uz = __uint_as_float(cv.z);
        float2 w01 = unp_h2(Tv.x);
        float2 w2_ = unp_h2(Tv.y);
        float sh20 = K1 * (ux * uy);
        float sh21 = K1 * (uy * uz);
        float sh22 = S5H * (uz * uz - 3.0f) * (1.0f / 3.0f);
        float sh23 = K1 * (ux * uz);
        float sh24 = K2 * (ux * ux - uy * uy);
        a0 += w01.x * pv;
        float w1p = w01.y * pv, w2p = w2_.x * pv;
        a10 += w1p * ux; a11 += w1p * uy; a12 += w1p * uz;
        a20 += w2p * sh20; a21 += w2p * sh21; a22 += w2p * sh22;
        a23 += w2p * sh23; a24 += w2p * sh24;
    };
    if (n < N) {
        int e0 = row_start[n], e1 = row_start[n + 1];
        int plen = e1 - e0;
        if (lane < 16) xr0 = x0c[(size_t)n * 16 + lane];
        if (ldx12) {
            if (lane < 48) xr1 = __half2float(x1c[(size_t)n * 48 + lane]);
            xr2 = __half2float(x2c[(size_t)n * 80 + lane]);
            if (lane < 16) xr2b = __half2float(x2c[(size_t)n * 80 + 64 + lane]);
        }
        if (plen > 0) {
            // ---- stage CSR row into LDS via async DMA (lane-contiguous dest) ----
            __builtin_amdgcn_global_load_lds(
                (const __attribute__((address_space(1))) void*)(csr + e0 + lane),
                (__attribute__((address_space(3))) void*)(&ROW[wid][0]), 16, 0, 0);
            if (plen > 64)
                __builtin_amdgcn_global_load_lds(
                    (const __attribute__((address_space(1))) void*)(csr + e0 + 64 + lane),
                    (__attribute__((address_space(3))) void*)(&ROW[wid][64]), 16, 0, 0);
            asm volatile("s_waitcnt vmcnt(0)" ::: "memory");
            const uint4* RB = ROW[wid];
            int L = (plen + 3) >> 2;         // 4-edge groups (padded rows: even)
            int Lm = L < 32 ? L : 32;        // LDS covers 128 edges
            // ---- 4-deep LDS window + 3-deep global (p0/tb2) pipeline ----
            uint4 c0 = RB[g];
            uint4 c1 = RB[4 + g];
            uint4 c2 = RB[8 + g];
            uint4 c3 = RB[12 + g];
            float p0v = p0g[(c0.x & 0xffffu) * 16 + c];
            uint2 T0  = tb2[((c0.x >> 16) & 0xfff0u) | c];
            float p1v = p0g[(c1.x & 0xffffu) * 16 + c];
            uint2 T1  = tb2[((c1.x >> 16) & 0xfff0u) | c];
            float p2v = p0g[(c2.x & 0xffffu) * 16 + c];
            uint2 T2  = tb2[((c2.x >> 16) & 0xfff0u) | c];
            #pragma unroll 2
            for (int k = 0; k < Lm; ++k) {
                uint4 c4 = RB[(k + 4) * 4 + g];
                float p3v = p0g[(c3.x & 0xffffu) * 16 + c];
                uint2 T3  = tb2[((c3.x >> 16) & 0xfff0u) | c];
                EDGE(c0, p0v, T0);
                c0 = c1; c1 = c2; c2 = c3; c3 = c4;
                p0v = p1v; T0 = T1; p1v = p2v; T1 = T2; p2v = p3v; T2 = T3;
            }
            if (plen > 128) {   // rare fallback beyond LDS window
                for (int j = e0 + 128 + g; j < e1; j += 4) {
                    uint4 cx = csr[j];
                    float pv = p0g[(cx.x & 0xffffu) * 16 + c];
                    uint2 Tx = tb2[((cx.x >> 16) & 0xfff0u) | c];
                    EDGE(cx, pv, Tx);
                }
            }
        }
    }
    #pragma unroll
    for (int m = 16; m < 64; m <<= 1) {
        a0  += __shfl_xor(a0, m);
        a10 += __shfl_xor(a10, m); a11 += __shfl_xor(a11, m); a12 += __shfl_xor(a12, m);
        a20 += __shfl_xor(a20, m); a21 += __shfl_xor(a21, m); a22 += __shfl_xor(a22, m);
        a23 += __shfl_xor(a23, m); a24 += __shfl_xor(a24, m);
    }
    float* A = AGG[wid];
    if (lane < 16) {
        A[c] = a0 * INVS;
        A[16 + c * 3 + 0] = a10 * INVS; A[16 + c * 3 + 1] = a11 * INVS; A[16 + c * 3 + 2] = a12 * INVS;
        A[64 + c * 5 + 0] = a20 * INVS; A[64 + c * 5 + 1] = a21 * INVS; A[64 + c * 5 + 2] = a22 * INVS;
        A[64 + c * 5 + 3] = a23 * INVS; A[64 + c * 5 + 4] = a24 * INVS;
    }
    {
        float* X = XIN[wid];
        if (lane < 16) X[lane] = xr0;
        if (lane < 48) X[16 + lane] = xr1;
        X[64 + lane] = xr2;
        if (lane < 16) X[128 + lane] = xr2b;
    }
    __syncthreads();
    if (n >= N) return;
    const float* X = XIN[wid];
    float act = 0.0f;
    if (lane < 48) {
        float sj = 0.0f;
        #pragma unroll
        for (int cc = 0; cc < 16; ++cc)
            sj += X[cc] * Wsc[cc * 48 + lane] + A[cc] * Wa[cc * 48 + lane];
        float sg = sigmoidf_(sj);
        act = (lane < 16) ? sj * sg : sg;
    }
    if (lane < 16) x0n[(size_t)n * 16 + lane] = act;
    // p0 for next layer: p0out[n][m] = sum_cc act[cc] * P0n[cc][m]
    if (wp0) {
        float pn = 0.0f;
        #pragma unroll
        for (int cc = 0; cc < 16; ++cc) pn += __shfl(act, cc) * P0n[cc * 16 + (lane & 15)];
        if (lane < 16) p0out[(size_t)n * 16 + lane] = pn;
    }
    {
        int d = lane >> 4, m = lane & 15;
        float v = 0.0f;
        if (lane < 48) {
            if (ldx12) {
                #pragma unroll
                for (int cc = 0; cc < 16; ++cc) v += X[16 + cc * 3 + d] * W1m[cc * 16 + m];
            }
            v += A[16 + m * 3 + d];
        }
        float sg1 = __shfl(act, 16 + m);
        if (lane < 48) x1n[(size_t)n * 48 + m * 3 + d] = __float2half(v * sg1);
    }
    #pragma unroll
    for (int ch = 0; ch < 2; ++ch) {
        int idx = ch * 64 + lane;
        int d = idx >> 4, m = idx & 15;
        bool on = idx < 80;
        float v = 0.0f;
        if (on) {
            if (ldx12) {
                #pragma unroll
                for (int cc = 0; cc < 16; ++cc) v += X[64 + cc * 5 + d] * W2m[cc * 16 + m];
            }
            v += A[64 + m * 5 + d];
        }
        float sg2 = __shfl(act, 32 + (m & 15));
        if (on) x2n[(size_t)n * 80 + m * 5 + d] = __float2half(v * sg2);
    }
}

// ---------------- final reduction ----------------
__global__ void k_out1(const float* __restrict__ x0, const float* __restrict__ Wout,
                       float* __restrict__ partial, int N) {
    __shared__ float red[256];
    int tid = threadIdx.x;
    float s = 0.0f;
    for (int n = blockIdx.x * blockDim.x + tid; n < N; n += gridDim.x * blockDim.x) {
        float acc = 0.0f;
        #pragma unroll
        for (int cc = 0; cc < 16; ++cc) acc += x0[n * 16 + cc] * Wout[cc];
        s += acc;
    }
    red[tid] = s;
    __syncthreads();
    for (int off = 128; off > 0; off >>= 1) {
        if (tid < off) red[tid] += red[tid + off];
        __syncthreads();
    }
    if (tid == 0) partial[blockIdx.x] = red[0];
}

__global__ void k_out2(const float* __restrict__ partial, float* __restrict__ out,
                       int nb, float scale) {
    __shared__ float red[256];
    int tid = threadIdx.x;
    red[tid] = (tid < nb) ? partial[tid] : 0.0f;
    __syncthreads();
    for (int off = 128; off > 0; off >>= 1) {
        if (tid < off) red[tid] += red[tid + off];
        __syncthreads();
    }
    if (tid == 0) out[0] = red[0] * scale;
}

extern "C" void kernel_launch(void* const* d_in, const int* in_sizes, int n_in,
                              void* d_out, int out_size, void* d_ws, size_t ws_size,
                              hipStream_t stream) {
    const float* pos = (const float*)d_in[0];
    const float* x   = (const float*)d_in[1];
    const int* esrc  = (const int*)d_in[2];
    const int* edst  = (const int*)d_in[3];
    const float* mlp_w1 = (const float*)d_in[5];
    const float* mlp_b1 = (const float*)d_in[6];
    const float* mlp_w2 = (const float*)d_in[7];
    const float* P0  = (const float*)d_in[8];
    const float* Wsc = (const float*)d_in[9];
    const float* Wa  = (const float*)d_in[10];
    const float* W1m = (const float*)d_in[11];
    const float* W2m = (const float*)d_in[12];
    const float* Wout = (const float*)d_in[13];
    int N = in_sizes[0] / 3;
    int E = in_sizes[2];
    int cap = E + 8 * N + 256;
    int nbuck = (N + 127) >> 7;

    char* ws = (char*)d_ws;
    size_t off = 0;
    auto alloc = [&](size_t bytes) -> void* {
        void* p = ws + off;
        off += (bytes + 255) & ~(size_t)255;
        return p;
    };
    int*    cnt       = (int*)alloc((size_t)N * 4);
    int*    row_start = (int*)alloc((size_t)(N + 1) * 4);
    int*    cursor    = (int*)alloc((size_t)N * 4);
    int*    bsum      = (int*)alloc(256 * 4);
    int*    boff      = (int*)alloc(256 * 4);
    int*    bhist     = (int*)alloc(512 * 4);
    int*    bbase     = (int*)alloc(513 * 4);
    int*    bcursor   = (int*)alloc(512 * 4);
    uint4*  csr       = (uint4*)alloc((size_t)cap * 16);
    uint2*  tb2       = (uint2*)alloc((size_t)3 * TSZ2 * 16 * 8);
    float*  p0A = (float*)alloc((size_t)65536 * 16 * 4);   // src is 16-bit
    float*  p0B = (float*)alloc((size_t)65536 * 16 * 4);
    float*  x0A = (float*)alloc((size_t)N * 16 * 4);
    float*  x0B = (float*)alloc((size_t)N * 16 * 4);
    __half* x1B = (__half*)alloc((size_t)N * 48 * 2);
    __half* x2B = (__half*)alloc((size_t)N * 80 * 2);
    // union region: bbuf (setup-only) aliases x1A + x2A (first written in layer 1... l=0 writes B)
    size_t x1Asz = ((size_t)N * 48 * 2 + 255) & ~(size_t)255;
    size_t unionSz = x1Asz + (size_t)N * 80 * 2;
    size_t bbufSz = (size_t)E * 16;
    char*  unionA = (char*)alloc(unionSz > bbufSz ? unionSz : bbufSz);
    __half* x1A = (__half*)unionA;
    __half* x2A = (__half*)(unionA + x1Asz);
    uint4* bbuf = (uint4*)unionA;
    float*  partial = (float*)alloc(256 * 4);

    int nbscan = (N + SCB - 1) / SCB;
    int nchunk = (E + CHK - 1) / CHK;

    k_table<<<3 * (TSZ2 / 32), 256, 0, stream>>>(mlp_w1, mlp_b1, mlp_w2, tb2, cnt, bhist, N);
    k_hist<<<nchunk, 256, 0, stream>>>(edst, cnt, bhist, E, x, P0, p0A, N);
    k_scanA<<<nbscan, 256, 0, stream>>>(cnt, bsum, N);
    k_scans<<<2, 512, 0, stream>>>(bsum, boff, nbscan, bhist, bbase, bcursor, nbuck, E);
    k_scanC<<<nbscan, 256, 0, stream>>>(cnt, boff, row_start, cursor, N);
    k_scat1<<<nchunk, 256, 0, stream>>>(pos, esrc, edst, bcursor, bbuf, E, nbuck);
    k_scat2<<<nbuck, 256, 0, stream>>>(bbuf, bbase, cursor, row_start, csr, N);

    float* x0bufs[2] = {x0A, x0B};
    __half* x1bufs[2] = {x1A, x1B};
    __half* x2bufs[2] = {x2A, x2B};
    float* p0bufs[2] = {p0A, p0B};
    for (int l = 0; l < 3; ++l) {
        const float* x0c = (l == 0) ? x : x0bufs[l & 1];
        const __half* x1c = x1bufs[l & 1];
        const __half* x2c = x2bufs[l & 1];
        float* x0n = x0bufs[(l & 1) ^ 1];
        __half* x1n = x1bufs[(l & 1) ^ 1];
        __half* x2n = x2bufs[(l & 1) ^ 1];
        const float* p0c = p0bufs[l & 1];
        float* p0n = p0bufs[(l & 1) ^ 1];
        const float* P0next = (l < 2) ? (P0 + (l + 1) * 256) : P0;
        k_aggupd<<<(N + 3) / 4, 256, 0, stream>>>(
            row_start, csr, tb2 + (size_t)l * TSZ2 * 16, p0c,
            x0c, x1c, x2c, x0n, x1n, x2n, p0n,
            Wsc + l * 768, Wa + l * 768,
            W1m + l * 256, W2m + l * 256, P0next, N,
            (l == 0) ? 0 : 1, (l < 2) ? 1 : 0);
    }
    float scale = (float)(1.0 / sqrt((double)N));
    k_out1<<<256, 256, 0, stream>>>(x0bufs[1], Wout, partial, N);
    k_out2<<<1, 256, 0, stream>>>(partial, (float*)d_out, 256, scale);
}

// Round 13
// 277.339 us; speedup vs baseline: 1.7989x; 1.3746x over previous
//
#include <hip/hip_runtime.h>
#include <hip/hip_fp16.h>
#include <math.h>

#define TSZ2 4096
#define RMAXF 2.0f
#define NBAS 10
#define HID 100
#define CHK 4096   // edges per binning block

__device__ __forceinline__ float sigmoidf_(float z) { return 1.0f / (1.0f + __expf(-z)); }
__device__ __forceinline__ float2 unp_h2(unsigned u) {
    __half2 h = __builtin_bit_cast(__half2, u);
    return __half22float2(h);
}
__device__ __forceinline__ unsigned pk_h2(float a, float b) {
    return __builtin_bit_cast(unsigned, __floats2half2_rn(a, b));
}

// ---------------- radial table fused with packing: tb2[l][t][c] {h2(w0,w1), h2(w2,0)} ----------------
// also zeroes bhist (runs before k_hist)
__global__ void k_table(const float* __restrict__ w1, const float* __restrict__ b1,
                        const float* __restrict__ w2, uint2* __restrict__ tb2,
                        int* __restrict__ bhist) {
    int gtid = blockIdx.x * 256 + threadIdx.x;
    if (gtid < 512) bhist[gtid] = 0;

    int l = blockIdx.x >> 7;
    int t0 = (blockIdx.x & 127) * 32;
    __shared__ float emb[32][NBAS];
    __shared__ float h[32][HID];
    __shared__ float w2s[HID * 48];
    __shared__ float wout[32][48];
    int tid = threadIdx.x;
    for (int i = tid; i < HID * 48; i += 256) w2s[i] = w2[l * HID * 48 + i];
    for (int i = tid; i < 32 * NBAS; i += 256) {
        int tt = i / NBAS, bi = i % NBAS;
        float r = (16.0f * (t0 + tt) + 7.5f) * (RMAXF / 65535.0f);
        float d = (r - (bi + 0.5f) * 0.2f) * 5.0f;
        emb[tt][bi] = (fabsf(d) < 1.0f) ? cosf(1.5707963267948966f * d) * 3.1622776601683795f : 0.0f;
    }
    __syncthreads();
    for (int i = tid; i < 32 * HID; i += 256) {
        int tt = i / HID, hh = i % HID;
        float z = b1[l * HID + hh];
        #pragma unroll
        for (int bi = 0; bi < NBAS; ++bi) z += emb[tt][bi] * w1[(l * NBAS + bi) * HID + hh];
        h[tt][hh] = z * sigmoidf_(z);
    }
    __syncthreads();
    for (int i = tid; i < 32 * 48; i += 256) {
        int tt = i / 48, j = i % 48;
        float o = 0.0f;
        for (int k = 0; k < HID; ++k) o += h[tt][k] * w2s[k * 48 + j];
        wout[tt][j] = o;
    }
    __syncthreads();
    for (int i = tid; i < 32 * 16; i += 256) {
        int tt = i >> 4, c = i & 15;
        int t = t0 + tt;
        uint2 o = make_uint2(0, 0);
        if (t != TSZ2 - 1) {   // last row stays zero = sentinel
            o.x = pk_h2(wout[tt][c], wout[tt][16 + c]);
            o.y = pk_h2(wout[tt][32 + c], 0.0f);
        }
        tb2[((size_t)l * TSZ2 + t) * 16 + c] = o;
    }
}

// ---------------- bucket histogram (LDS-agg only) + fused p0 (layer 0, fp16) ----------------
__global__ void k_hist(const int* __restrict__ edst, int* bhist, int E,
                       const float* __restrict__ x0, const float* __restrict__ P0l,
                       __half* __restrict__ p0, int N) {
    __shared__ int lb[512];
    int tid = threadIdx.x;
    for (int i = tid; i < 512; i += 256) lb[i] = 0;
    __syncthreads();
    int e0 = blockIdx.x * CHK;
    #pragma unroll
    for (int k = 0; k < CHK / 256; ++k) {
        int e = e0 + k * 256 + tid;
        if (e < E) atomicAdd(&lb[edst[e] >> 7], 1);
    }
    // fused p0 = x0 @ P0[0]
    for (int i = blockIdx.x * 256 + tid; i < N * 16; i += gridDim.x * 256) {
        int n = i >> 4, m = i & 15;
        float acc = 0.0f;
        #pragma unroll
        for (int c = 0; c < 16; ++c) acc += x0[n * 16 + c] * P0l[c * 16 + m];
        p0[i] = __float2half(acc);
    }
    __syncthreads();
    for (int i = tid; i < 512; i += 256) if (lb[i]) atomicAdd(&bhist[i], lb[i]);
}

// ---------------- bucket scan (1 block, 512 threads) ----------------
__global__ void k_bscan(const int* __restrict__ bhist, int* __restrict__ bbase,
                        int* __restrict__ bcursor, int nbuck, int E) {
    __shared__ int part[512];
    int t = threadIdx.x;
    part[t] = (t < nbuck) ? bhist[t] : 0;
    __syncthreads();
    for (int off = 1; off < 512; off <<= 1) {
        int v = (t >= off) ? part[t - off] : 0;
        __syncthreads();
        part[t] += v;
        __syncthreads();
    }
    int ex = (t == 0) ? 0 : part[t - 1];
    if (t < nbuck) { bbase[t] = ex; bcursor[t] = ex; }
    if (t == 0) bbase[nbuck] = E;
}

// ---------------- phase 1: bin edges into dst-buckets with geometry, burst writes ----------------
__global__ void k_scat1(const float* __restrict__ pos, const int* __restrict__ esrc,
                        const int* __restrict__ edst, int* __restrict__ bcursor,
                        uint4* __restrict__ bbuf, int E, int nbuck) {
    __shared__ int lcnt[512];
    __shared__ int base[512];
    int tid = threadIdx.x;
    for (int i = tid; i < 512; i += 256) lcnt[i] = 0;
    __syncthreads();
    int e0 = blockIdx.x * CHK;
    #pragma unroll
    for (int k = 0; k < CHK / 256; ++k) {
        int e = e0 + k * 256 + tid;
        if (e < E) atomicAdd(&lcnt[edst[e] >> 7], 1);
    }
    __syncthreads();
    for (int b = tid; b < nbuck; b += 256)
        base[b] = lcnt[b] ? atomicAdd(&bcursor[b], lcnt[b]) : 0;
    __syncthreads();
    #pragma unroll
    for (int k = 0; k < CHK / 256; ++k) {
        int e = e0 + k * 256 + tid;
        if (e >= E) continue;
        int s = esrc[e], d = edst[e];
        float vx = pos[s * 3 + 0] - pos[d * 3 + 0];
        float vy = pos[s * 3 + 1] - pos[d * 3 + 1];
        float vz = pos[s * 3 + 2] - pos[d * 3 + 2];
        float r = sqrtf(vx * vx + vy * vy + vz * vz);
        float kf = 1.7320508075688772f / (r + 1e-12f);   // sqrt(3)/r premult
        unsigned rtfix = (unsigned)fminf(r * (65535.0f / RMAXF) + 0.5f, 65535.0f);
        uint4 o;
        o.x = (unsigned)s | (rtfix << 16);
        o.y = pk_h2(vx * kf, vy * kf);
        o.z = __float_as_uint(vz * kf);
        o.w = (unsigned)d;
        int slot = atomicAdd(&base[d >> 7], 1);
        bbuf[slot] = o;
    }
}

// ---------------- phase 2: bucket counting-sort -> padded CSR + row_start/rlen + padfill ----------------
__global__ void k_scat2(const uint4* __restrict__ bbuf, const int* __restrict__ bbase,
                        uint4* __restrict__ csr, int* __restrict__ row_start,
                        int* __restrict__ rlen, int N) {
    int b = blockIdx.x;
    int tid = threadIdx.x;
    __shared__ int cnt128[128];
    __shared__ int base128[128];
    __shared__ int cur[128];
    __shared__ int part[128];
    if (tid < 128) cnt128[tid] = 0;
    __syncthreads();
    int j0 = bbase[b], j1 = bbase[b + 1];
    int n0 = b << 7;
    // pass 1: per-node counts
    for (int j = j0 + tid; j < j1; j += 256)
        atomicAdd(&cnt128[((int)bbuf[j].w) & 127], 1);
    __syncthreads();
    // exclusive scan of pad-4 counts over 128 entries
    if (tid < 128) part[tid] = (cnt128[tid] + 3) & ~3;
    __syncthreads();
    for (int off = 1; off < 128; off <<= 1) {
        int v = 0;
        if (tid < 128 && tid >= off) v = part[tid - off];
        __syncthreads();
        if (tid < 128) part[tid] += v;
        __syncthreads();
    }
    int pbase = j0 + 512 * b;   // padded base: bbase[b] + per-bucket pad slack
    if (tid < 128) {
        int ex = pbase + ((tid == 0) ? 0 : part[tid - 1]);
        base128[tid] = ex;
        cur[tid] = ex;
        int n = n0 + tid;
        if (n < N) {
            row_start[n] = ex;
            rlen[n] = (cnt128[tid] + 3) & ~3;
        }
    }
    __syncthreads();
    // pass 2: scatter into exact padded slots; repack w = src*32 (byte offset into fp16 p0 row)
    for (int j = j0 + tid; j < j1; j += 256) {
        uint4 e = bbuf[j];
        int local = ((int)e.w) & 127;
        int slot = atomicAdd(&cur[local], 1);
        e.w = (e.x & 0xffffu) << 5;
        csr[slot] = e;
    }
    __syncthreads();
    // sentinel padfill (<=3 per node)
    if (tid < 128) {
        int end = base128[tid] + ((cnt128[tid] + 3) & ~3);
        uint4 sent = make_uint4(0xFFFF0000u, 0, 0, 0);
        for (int s = cur[tid]; s < end; ++s) csr[s] = sent;
    }
}

// ---------------- fused aggregation + node update; wave per node, barrier-free ----------------
__launch_bounds__(256)
__global__ void k_aggupd(const int* __restrict__ row_start, const int* __restrict__ rlen,
                         const uint4* __restrict__ csr,
                         const uint2* __restrict__ tb2, const __half* __restrict__ p0g,
                         const float* __restrict__ x0c, const __half* __restrict__ x1c,
                         const __half* __restrict__ x2c,
                         float* __restrict__ x0n, __half* __restrict__ x1n, __half* __restrict__ x2n,
                         __half* __restrict__ p0out,
                         const float* __restrict__ Wsc, const float* __restrict__ Wa,
                         const float* __restrict__ W1m, const float* __restrict__ W2m,
                         const float* __restrict__ P0n,
                         int N, int ldx12, int wp0) {
    const float INVS = 0.17677669529663687f;  // 1/sqrt(32)
    const float K1  = 1.2909944487358056f;    // sqrt(15)/3
    const float S5H = 1.118033988749895f;     // sqrt(5)/2
    const float K2  = 0.6454972243679028f;    // sqrt(15)/2/3
    __shared__ uint4 ROW[4][144];   // per-wave CSR row buffer (128 edges + overrun slack)
    __shared__ float AGG[4][144];
    __shared__ float XIN[4][144];
    int tid = threadIdx.x;
    int wid = tid >> 6;
    int lane = tid & 63;
    int n = blockIdx.x * 4 + wid;
    if (n >= N) return;
    int g = lane >> 4, c = lane & 15;
    unsigned c2 = (unsigned)(c << 1);
    const char* p0b = (const char*)p0g;
    float a0 = 0, a10 = 0, a11 = 0, a12 = 0, a20 = 0, a21 = 0, a22 = 0, a23 = 0, a24 = 0;
    float xr0 = 0, xr1 = 0, xr2 = 0, xr2b = 0;
    auto P0LD = [&](unsigned w) -> float {
        return __half2float(*(const __half*)(p0b + ((w & 0x1FFFFFu) | c2)));
    };
    auto EDGE = [&](uint4 cv, float pv, uint2 Tv) {
        float2 uxy = unp_h2(cv.y);
        float ux = uxy.x, uy = uxy.y, uz = __uint_as_float(cv.z);
        float2 w01 = unp_h2(Tv.x);
        float2 w2_ = unp_h2(Tv.y);
        float sh20 = K1 * (ux * uy);
        float sh21 = K1 * (uy * uz);
        float sh22 = S5H * (uz * uz - 3.0f) * (1.0f / 3.0f);
        float sh23 = K1 * (ux * uz);
        float sh24 = K2 * (ux * ux - uy * uy);
        a0 += w01.x * pv;
        float w1p = w01.y * pv, w2p = w2_.x * pv;
        a10 += w1p * ux; a11 += w1p * uy; a12 += w1p * uz;
        a20 += w2p * sh20; a21 += w2p * sh21; a22 += w2p * sh22;
        a23 += w2p * sh23; a24 += w2p * sh24;
    };
    {
        int e0 = row_start[n];
        int plen = rlen[n];
        if (lane < 16) xr0 = x0c[(size_t)n * 16 + lane];
        if (ldx12) {
            if (lane < 48) xr1 = __half2float(x1c[(size_t)n * 48 + lane]);
            xr2 = __half2float(x2c[(size_t)n * 80 + lane]);
            if (lane < 16) xr2b = __half2float(x2c[(size_t)n * 80 + 64 + lane]);
        }
        if (plen > 0) {
            // ---- stage CSR row into LDS via async DMA (lane-contiguous dest) ----
            __builtin_amdgcn_global_load_lds(
                (const __attribute__((address_space(1))) void*)(csr + e0 + lane),
                (__attribute__((address_space(3))) void*)(&ROW[wid][0]), 16, 0, 0);
            if (plen > 64)
                __builtin_amdgcn_global_load_lds(
                    (const __attribute__((address_space(1))) void*)(csr + e0 + 64 + lane),
                    (__attribute__((address_space(3))) void*)(&ROW[wid][64]), 16, 0, 0);
            asm volatile("s_waitcnt vmcnt(0)" ::: "memory");
            const uint4* RB = ROW[wid];
            int L = plen >> 2;               // pad-4 rows: exact group count
            int Lm = L < 32 ? L : 32;        // LDS covers 128 edges
            // ---- 4-deep LDS window + 3-deep global (p0/tb2) pipeline ----
            uint4 c0 = RB[g];
            uint4 c1 = RB[4 + g];
            uint4 c2v = RB[8 + g];
            uint4 c3 = RB[12 + g];
            float p0v = P0LD(c0.w);
            uint2 T0  = tb2[((c0.x >> 16) & 0xfff0u) | c];
            float p1v = P0LD(c1.w);
            uint2 T1  = tb2[((c1.x >> 16) & 0xfff0u) | c];
            float p2v = P0LD(c2v.w);
            uint2 T2  = tb2[((c2v.x >> 16) & 0xfff0u) | c];
            #pragma unroll 2
            for (int k = 0; k < Lm; ++k) {
                uint4 c4 = RB[(k + 4) * 4 + g];
                float p3v = P0LD(c3.w);
                uint2 T3  = tb2[((c3.x >> 16) & 0xfff0u) | c];
                EDGE(c0, p0v, T0);
                c0 = c1; c1 = c2v; c2v = c3; c3 = c4;
                p0v = p1v; T0 = T1; p1v = p2v; T1 = T2; p2v = p3v; T2 = T3;
            }
            if (plen > 128) {   // rare fallback beyond LDS window
                for (int j = e0 + 128 + g; j < e0 + plen; j += 4) {
                    uint4 cx = csr[j];
                    float pv = P0LD(cx.w);
                    uint2 Tx = tb2[((cx.x >> 16) & 0xfff0u) | c];
                    EDGE(cx, pv, Tx);
                }
            }
        }
    }
    #pragma unroll
    for (int m = 16; m < 64; m <<= 1) {
        a0  += __shfl_xor(a0, m);
        a10 += __shfl_xor(a10, m); a11 += __shfl_xor(a11, m); a12 += __shfl_xor(a12, m);
        a20 += __shfl_xor(a20, m); a21 += __shfl_xor(a21, m); a22 += __shfl_xor(a22, m);
        a23 += __shfl_xor(a23, m); a24 += __shfl_xor(a24, m);
    }
    float* A = AGG[wid];
    if (lane < 16) {
        A[c] = a0 * INVS;
        A[16 + c * 3 + 0] = a10 * INVS; A[16 + c * 3 + 1] = a11 * INVS; A[16 + c * 3 + 2] = a12 * INVS;
        A[64 + c * 5 + 0] = a20 * INVS; A[64 + c * 5 + 1] = a21 * INVS; A[64 + c * 5 + 2] = a22 * INVS;
        A[64 + c * 5 + 3] = a23 * INVS; A[64 + c * 5 + 4] = a24 * INVS;
    }
    {
        float* X = XIN[wid];
        if (lane < 16) X[lane] = xr0;
        if (lane < 48) X[16 + lane] = xr1;
        X[64 + lane] = xr2;
        if (lane < 16) X[128 + lane] = xr2b;
    }
    // wave-private LDS slices: same-wave DS ordering suffices, no barrier needed
    const float* X = XIN[wid];
    float act = 0.0f;
    if (lane < 48) {
        float sj = 0.0f;
        #pragma unroll
        for (int cc = 0; cc < 16; ++cc)
            sj += X[cc] * Wsc[cc * 48 + lane] + A[cc] * Wa[cc * 48 + lane];
        float sg = sigmoidf_(sj);
        act = (lane < 16) ? sj * sg : sg;
    }
    if (lane < 16) x0n[(size_t)n * 16 + lane] = act;
    // p0 for next layer: p0out[n][m] = sum_cc act[cc] * P0n[cc][m]
    if (wp0) {
        float pn = 0.0f;
        #pragma unroll
        for (int cc = 0; cc < 16; ++cc) pn += __shfl(act, cc) * P0n[cc * 16 + (lane & 15)];
        if (lane < 16) p0out[(size_t)n * 16 + lane] = __float2half(pn);
    }
    {
        int d = lane >> 4, m = lane & 15;
        float v = 0.0f;
        if (lane < 48) {
            if (ldx12) {
                #pragma unroll
                for (int cc = 0; cc < 16; ++cc) v += X[16 + cc * 3 + d] * W1m[cc * 16 + m];
            }
            v += A[16 + m * 3 + d];
        }
        float sg1 = __shfl(act, 16 + m);
        if (lane < 48) x1n[(size_t)n * 48 + m * 3 + d] = __float2half(v * sg1);
    }
    #pragma unroll
    for (int ch = 0; ch < 2; ++ch) {
        int idx = ch * 64 + lane;
        int d = idx >> 4, m = idx & 15;
        bool on = idx < 80;
        float v = 0.0f;
        if (on) {
            if (ldx12) {
                #pragma unroll
                for (int cc = 0; cc < 16; ++cc) v += X[64 + cc * 5 + d] * W2m[cc * 16 + m];
            }
            v += A[64 + m * 5 + d];
        }
        float sg2 = __shfl(act, 32 + (m & 15));
        if (on) x2n[(size_t)n * 80 + m * 5 + d] = __float2half(v * sg2);
    }
}

// ---------------- final reduction ----------------
__global__ void k_out1(const float* __restrict__ x0, const float* __restrict__ Wout,
                       float* __restrict__ partial, int N) {
    __shared__ float red[256];
    int tid = threadIdx.x;
    float s = 0.0f;
    for (int n = blockIdx.x * blockDim.x + tid; n < N; n += gridDim.x * blockDim.x) {
        float acc = 0.0f;
        #pragma unroll
        for (int cc = 0; cc < 16; ++cc) acc += x0[n * 16 + cc] * Wout[cc];
        s += acc;
    }
    red[tid] = s;
    __syncthreads();
    for (int off = 128; off > 0; off >>= 1) {
        if (tid < off) red[tid] += red[tid + off];
        __syncthreads();
    }
    if (tid == 0) partial[blockIdx.x] = red[0];
}

__global__ void k_out2(const float* __restrict__ partial, float* __restrict__ out,
                       int nb, float scale) {
    __shared__ float red[256];
    int tid = threadIdx.x;
    red[tid] = (tid < nb) ? partial[tid] : 0.0f;
    __syncthreads();
    for (int off = 128; off > 0; off >>= 1) {
        if (tid < off) red[tid] += red[tid + off];
        __syncthreads();
    }
    if (tid == 0) out[0] = red[0] * scale;
}

extern "C" void kernel_launch(void* const* d_in, const int* in_sizes, int n_in,
                              void* d_out, int out_size, void* d_ws, size_t ws_size,
                              hipStream_t stream) {
    const float* pos = (const float*)d_in[0];
    const float* x   = (const float*)d_in[1];
    const int* esrc  = (const int*)d_in[2];
    const int* edst  = (const int*)d_in[3];
    const float* mlp_w1 = (const float*)d_in[5];
    const float* mlp_b1 = (const float*)d_in[6];
    const float* mlp_w2 = (const float*)d_in[7];
    const float* P0  = (const float*)d_in[8];
    const float* Wsc = (const float*)d_in[9];
    const float* Wa  = (const float*)d_in[10];
    const float* W1m = (const float*)d_in[11];
    const float* W2m = (const float*)d_in[12];
    const float* Wout = (const float*)d_in[13];
    int N = in_sizes[0] / 3;
    int E = in_sizes[2];
    int nbuck = (N + 127) >> 7;
    int cap = E + 512 * nbuck + 256;

    char* ws = (char*)d_ws;
    size_t off = 0;
    auto alloc = [&](size_t bytes) -> void* {
        void* p = ws + off;
        off += (bytes + 255) & ~(size_t)255;
        return p;
    };
    int*    row_start = (int*)alloc((size_t)N * 4);
    int*    rlen      = (int*)alloc((size_t)N * 4);
    int*    bhist     = (int*)alloc(512 * 4);
    int*    bbase     = (int*)alloc(513 * 4);
    int*    bcursor   = (int*)alloc(512 * 4);
    uint4*  csr       = (uint4*)alloc((size_t)cap * 16);
    uint2*  tb2       = (uint2*)alloc((size_t)3 * TSZ2 * 16 * 8);
    __half* p0A = (__half*)alloc((size_t)65536 * 16 * 2);   // 2 MB: masked-offset safe
    __half* p0B = (__half*)alloc((size_t)65536 * 16 * 2);
    float*  x0A = (float*)alloc((size_t)N * 16 * 4);
    float*  x0B = (float*)alloc((size_t)N * 16 * 4);
    __half* x1B = (__half*)alloc((size_t)N * 48 * 2);
    __half* x2B = (__half*)alloc((size_t)N * 80 * 2);
    // union region: bbuf (setup-only) aliases x1A + x2A (first written in layer 0's output)
    size_t x1Asz = ((size_t)N * 48 * 2 + 255) & ~(size_t)255;
    size_t unionSz = x1Asz + (size_t)N * 80 * 2;
    size_t bbufSz = (size_t)E * 16;
    char*  unionA = (char*)alloc(unionSz > bbufSz ? unionSz : bbufSz);
    __half* x1A = (__half*)unionA;
    __half* x2A = (__half*)(unionA + x1Asz);
    uint4* bbuf = (uint4*)unionA;
    float*  partial = (float*)alloc(256 * 4);

    int nchunk = (E + CHK - 1) / CHK;

    k_table<<<3 * (TSZ2 / 32), 256, 0, stream>>>(mlp_w1, mlp_b1, mlp_w2, tb2, bhist);
    k_hist<<<nchunk, 256, 0, stream>>>(edst, bhist, E, x, P0, p0A, N);
    k_bscan<<<1, 512, 0, stream>>>(bhist, bbase, bcursor, nbuck, E);
    k_scat1<<<nchunk, 256, 0, stream>>>(pos, esrc, edst, bcursor, bbuf, E, nbuck);
    k_scat2<<<nbuck, 256, 0, stream>>>(bbuf, bbase, csr, row_start, rlen, N);

    float* x0bufs[2] = {x0A, x0B};
    __half* x1bufs[2] = {x1A, x1B};
    __half* x2bufs[2] = {x2A, x2B};
    __half* p0bufs[2] = {p0A, p0B};
    for (int l = 0; l < 3; ++l) {
        const float* x0c = (l == 0) ? x : x0bufs[l & 1];
        const __half* x1c = x1bufs[l & 1];
        const __half* x2c = x2bufs[l & 1];
        float* x0n = x0bufs[(l & 1) ^ 1];
        __half* x1n = x1bufs[(l & 1) ^ 1];
        __half* x2n = x2bufs[(l & 1) ^ 1];
        const __half* p0c = p0bufs[l & 1];
        __half* p0n = p0bufs[(l & 1) ^ 1];
        const float* P0next = (l < 2) ? (P0 + (l + 1) * 256) : P0;
        k_aggupd<<<(N + 3) / 4, 256, 0, stream>>>(
            row_start, rlen, csr, tb2 + (size_t)l * TSZ2 * 16, p0c,
            x0c, x1c, x2c, x0n, x1n, x2n, p0n,
            Wsc + l * 768, Wa + l * 768,
            W1m + l * 256, W2m + l * 256, P0next, N,
            (l == 0) ? 0 : 1, (l < 2) ? 1 : 0);
    }
    float scale = (float)(1.0 / sqrt((double)N));
    k_out1<<<256, 256, 0, stream>>>(x0bufs[1], Wout, partial, N);
    k_out2<<<1, 256, 0, stream>>>(partial, (float*)d_out, 256, scale);
}

// Round 14
// 167.342 us; speedup vs baseline: 2.9814x; 1.6573x over previous
//
#include <hip/hip_runtime.h>
#include <hip/hip_fp16.h>
#include <math.h>

#define TSZ2 4096
#define RMAXF 2.0f
#define NBAS 10
#define HID 100
#define CHK 4096   // edges per binning block

__device__ __forceinline__ float sigmoidf_(float z) { return 1.0f / (1.0f + __expf(-z)); }

// ---------------- radial table (ONLY w0: first 16 MLP outputs), fp16 [l][t][c] ----------------
// also zeroes bhist (runs before k_hist)
__global__ void k_table(const float* __restrict__ w1, const float* __restrict__ b1,
                        const float* __restrict__ w2, __half* __restrict__ tbh,
                        int* __restrict__ bhist) {
    int gtid = blockIdx.x * 256 + threadIdx.x;
    if (gtid < 512) bhist[gtid] = 0;

    int l = blockIdx.x >> 7;
    int t0 = (blockIdx.x & 127) * 32;
    __shared__ float emb[32][NBAS];
    __shared__ float h[32][HID];
    __shared__ float w2s[HID * 16];
    int tid = threadIdx.x;
    for (int i = tid; i < HID * 16; i += 256) {
        int k = i >> 4, j = i & 15;
        w2s[i] = w2[l * HID * 48 + k * 48 + j];   // only first 16 output cols are live
    }
    for (int i = tid; i < 32 * NBAS; i += 256) {
        int tt = i / NBAS, bi = i % NBAS;
        float r = (16.0f * (t0 + tt) + 7.5f) * (RMAXF / 65535.0f);
        float d = (r - (bi + 0.5f) * 0.2f) * 5.0f;
        emb[tt][bi] = (fabsf(d) < 1.0f) ? cosf(1.5707963267948966f * d) * 3.1622776601683795f : 0.0f;
    }
    __syncthreads();
    for (int i = tid; i < 32 * HID; i += 256) {
        int tt = i / HID, hh = i % HID;
        float z = b1[l * HID + hh];
        #pragma unroll
        for (int bi = 0; bi < NBAS; ++bi) z += emb[tt][bi] * w1[(l * NBAS + bi) * HID + hh];
        h[tt][hh] = z * sigmoidf_(z);
    }
    __syncthreads();
    for (int i = tid; i < 32 * 16; i += 256) {
        int tt = i >> 4, j = i & 15;
        int t = t0 + tt;
        float o = 0.0f;
        if (t != TSZ2 - 1) {   // last row stays zero = sentinel
            for (int k = 0; k < HID; ++k) o += h[tt][k] * w2s[k * 16 + j];
        }
        tbh[((size_t)l * TSZ2 + t) * 16 + j] = __float2half(o);
    }
}

// ---------------- bucket histogram (LDS-agg only) + fused p0 (layer 0, fp16) ----------------
__global__ void k_hist(const int* __restrict__ edst, int* bhist, int E,
                       const float* __restrict__ x0, const float* __restrict__ P0l,
                       __half* __restrict__ p0, int N) {
    __shared__ int lb[512];
    int tid = threadIdx.x;
    for (int i = tid; i < 512; i += 256) lb[i] = 0;
    __syncthreads();
    int e0 = blockIdx.x * CHK;
    #pragma unroll
    for (int k = 0; k < CHK / 256; ++k) {
        int e = e0 + k * 256 + tid;
        if (e < E) atomicAdd(&lb[edst[e] >> 7], 1);
    }
    // fused p0 = x0 @ P0[0]
    for (int i = blockIdx.x * 256 + tid; i < N * 16; i += gridDim.x * 256) {
        int n = i >> 4, m = i & 15;
        float acc = 0.0f;
        #pragma unroll
        for (int c = 0; c < 16; ++c) acc += x0[n * 16 + c] * P0l[c * 16 + m];
        p0[i] = __float2half(acc);
    }
    __syncthreads();
    for (int i = tid; i < 512; i += 256) if (lb[i]) atomicAdd(&bhist[i], lb[i]);
}

// ---------------- bucket scan (1 block, 512 threads) ----------------
__global__ void k_bscan(const int* __restrict__ bhist, int* __restrict__ bbase,
                        int* __restrict__ bcursor, int nbuck, int E) {
    __shared__ int part[512];
    int t = threadIdx.x;
    part[t] = (t < nbuck) ? bhist[t] : 0;
    __syncthreads();
    for (int off = 1; off < 512; off <<= 1) {
        int v = (t >= off) ? part[t - off] : 0;
        __syncthreads();
        part[t] += v;
        __syncthreads();
    }
    int ex = (t == 0) ? 0 : part[t - 1];
    if (t < nbuck) { bbase[t] = ex; bcursor[t] = ex; }
    if (t == 0) bbase[nbuck] = E;
}

// ---------------- phase 1: bin edges into dst-buckets, 8B entries ----------------
__global__ void k_scat1(const float* __restrict__ pos, const int* __restrict__ esrc,
                        const int* __restrict__ edst, int* __restrict__ bcursor,
                        uint2* __restrict__ bbuf, int E, int nbuck) {
    __shared__ int lcnt[512];
    __shared__ int base[512];
    int tid = threadIdx.x;
    for (int i = tid; i < 512; i += 256) lcnt[i] = 0;
    __syncthreads();
    int e0 = blockIdx.x * CHK;
    #pragma unroll
    for (int k = 0; k < CHK / 256; ++k) {
        int e = e0 + k * 256 + tid;
        if (e < E) atomicAdd(&lcnt[edst[e] >> 7], 1);
    }
    __syncthreads();
    for (int b = tid; b < nbuck; b += 256)
        base[b] = lcnt[b] ? atomicAdd(&bcursor[b], lcnt[b]) : 0;
    __syncthreads();
    #pragma unroll
    for (int k = 0; k < CHK / 256; ++k) {
        int e = e0 + k * 256 + tid;
        if (e >= E) continue;
        int s = esrc[e], d = edst[e];
        float vx = pos[s * 3 + 0] - pos[d * 3 + 0];
        float vy = pos[s * 3 + 1] - pos[d * 3 + 1];
        float vz = pos[s * 3 + 2] - pos[d * 3 + 2];
        float r = sqrtf(vx * vx + vy * vy + vz * vz);
        unsigned rtfix = (unsigned)fminf(r * (65535.0f / RMAXF) + 0.5f, 65535.0f);
        uint2 o;
        o.x = (unsigned)s | (rtfix << 16);
        o.y = (unsigned)d;
        int slot = atomicAdd(&base[d >> 7], 1);
        bbuf[slot] = o;
    }
}

// ---------------- phase 2: bucket counting-sort -> padded CSR(4B) + row_start/rlen + padfill ----------------
__global__ void k_scat2(const uint2* __restrict__ bbuf, const int* __restrict__ bbase,
                        unsigned* __restrict__ csr, int* __restrict__ row_start,
                        int* __restrict__ rlen, int N) {
    int b = blockIdx.x;
    int tid = threadIdx.x;
    __shared__ int cnt128[128];
    __shared__ int base128[128];
    __shared__ int cur[128];
    __shared__ int part[128];
    if (tid < 128) cnt128[tid] = 0;
    __syncthreads();
    int j0 = bbase[b], j1 = bbase[b + 1];
    int n0 = b << 7;
    for (int j = j0 + tid; j < j1; j += 256)
        atomicAdd(&cnt128[((int)bbuf[j].y) & 127], 1);
    __syncthreads();
    if (tid < 128) part[tid] = (cnt128[tid] + 3) & ~3;
    __syncthreads();
    for (int off = 1; off < 128; off <<= 1) {
        int v = 0;
        if (tid < 128 && tid >= off) v = part[tid - off];
        __syncthreads();
        if (tid < 128) part[tid] += v;
        __syncthreads();
    }
    int pbase = j0 + 512 * b;   // padded base: bbase[b] + per-bucket pad slack
    if (tid < 128) {
        int ex = pbase + ((tid == 0) ? 0 : part[tid - 1]);
        base128[tid] = ex;
        cur[tid] = ex;
        int n = n0 + tid;
        if (n < N) {
            row_start[n] = ex;
            rlen[n] = (cnt128[tid] + 3) & ~3;
        }
    }
    __syncthreads();
    for (int j = j0 + tid; j < j1; j += 256) {
        uint2 e = bbuf[j];
        int local = ((int)e.y) & 127;
        int slot = atomicAdd(&cur[local], 1);
        csr[slot] = e.x;
    }
    __syncthreads();
    // sentinel padfill (<=3 per node): rtfix=0xFFFF -> table row 4095 = zeros
    if (tid < 128) {
        int end = base128[tid] + ((cnt128[tid] + 3) & ~3);
        for (int s = cur[tid]; s < end; ++s) csr[s] = 0xFFFF0000u;
    }
}

// ---------------- fused aggregation + node update; wave per node, x0-path only ----------------
__launch_bounds__(256)
__global__ void k_aggupd(const int* __restrict__ row_start, const int* __restrict__ rlen,
                         const unsigned* __restrict__ csr,
                         const __half* __restrict__ tbh, const __half* __restrict__ p0g,
                         const float* __restrict__ x0c,
                         float* __restrict__ x0n, __half* __restrict__ p0out,
                         const float* __restrict__ Wsc, const float* __restrict__ Wa,
                         const float* __restrict__ P0n,
                         int N, int wp0) {
    const float INVS = 0.17677669529663687f;  // 1/sqrt(32)
    __shared__ unsigned ROW[4][96];   // 64-edge DMA window + prefetch overrun slack
    int tid = threadIdx.x;
    int wid = tid >> 6;
    int lane = tid & 63;
    int n = blockIdx.x * 4 + wid;
    if (n >= N) return;
    int g = lane >> 4, c = lane & 15;
    float a0 = 0.0f;
    float xr0 = 0.0f;
    if (lane < 16) xr0 = x0c[(size_t)n * 16 + lane];
    int e0 = row_start[n];
    int plen = rlen[n];
    if (plen > 0) {
        __builtin_amdgcn_global_load_lds(
            (const __attribute__((address_space(1))) void*)(csr + e0 + lane),
            (__attribute__((address_space(3))) void*)(&ROW[wid][0]), 4, 0, 0);
        asm volatile("s_waitcnt vmcnt(0)" ::: "memory");
        const unsigned* RB = ROW[wid];
        int L = plen >> 2;               // pad-4 rows: exact group count
        int Lm = L < 16 ? L : 16;        // LDS window covers 64 edges
        unsigned c0 = RB[g], c1 = RB[4 + g], c2v = RB[8 + g], c3 = RB[12 + g];
        float p0v = __half2float(p0g[(c0 & 0xffffu) * 16 + c]);
        float w0v = __half2float(tbh[(c0 >> 20) * 16 + c]);
        float p1v = __half2float(p0g[(c1 & 0xffffu) * 16 + c]);
        float w1v = __half2float(tbh[(c1 >> 20) * 16 + c]);
        float p2v = __half2float(p0g[(c2v & 0xffffu) * 16 + c]);
        float w2v = __half2float(tbh[(c2v >> 20) * 16 + c]);
        #pragma unroll 2
        for (int k = 0; k < Lm; ++k) {
            unsigned c4 = RB[(k + 4) * 4 + g];
            float p3v = __half2float(p0g[(c3 & 0xffffu) * 16 + c]);
            float w3v = __half2float(tbh[(c3 >> 20) * 16 + c]);
            a0 += w0v * p0v;
            c0 = c1; c1 = c2v; c2v = c3; c3 = c4;
            p0v = p1v; w0v = w1v;
            p1v = p2v; w1v = w2v;
            p2v = p3v; w2v = w3v;
        }
        if (plen > 64) {   // rare fallback beyond LDS window (Poisson(32): ~never)
            for (int j = e0 + 64 + g; j < e0 + plen; j += 4) {
                unsigned cx = csr[j];
                a0 += __half2float(tbh[(cx >> 20) * 16 + c]) *
                      __half2float(p0g[(cx & 0xffffu) * 16 + c]);
            }
        }
    }
    // reduce over the 4 edge slots (lane bits 4,5); lane&15 = channel
    a0 += __shfl_xor(a0, 16);
    a0 += __shfl_xor(a0, 32);
    a0 *= INVS;
    // tail: s_j = sum_cc x0[cc]*Wsc[cc*48+j] + agg0[cc]*Wa[cc*48+j]; split cc over 4 slots
    float sj = 0.0f;
    #pragma unroll
    for (int t = 0; t < 4; ++t) {
        int cc = g * 4 + t;
        float xv = __shfl(xr0, cc);
        float av = __shfl(a0, cc);
        sj += xv * Wsc[cc * 48 + c] + av * Wa[cc * 48 + c];
    }
    sj += __shfl_xor(sj, 16);
    sj += __shfl_xor(sj, 32);
    float act = sj * sigmoidf_(sj);
    if (lane < 16) x0n[(size_t)n * 16 + lane] = act;
    // p0 for next layer
    if (wp0) {
        float pn = 0.0f;
        #pragma unroll
        for (int t = 0; t < 4; ++t) {
            int cc = g * 4 + t;
            float av = __shfl(act, cc);
            pn += av * P0n[cc * 16 + c];
        }
        pn += __shfl_xor(pn, 16);
        pn += __shfl_xor(pn, 32);
        if (lane < 16) p0out[(size_t)n * 16 + lane] = __float2half(pn);
    }
}

// ---------------- final reduction ----------------
__global__ void k_out1(const float* __restrict__ x0, const float* __restrict__ Wout,
                       float* __restrict__ partial, int N) {
    __shared__ float red[256];
    int tid = threadIdx.x;
    float s = 0.0f;
    for (int n = blockIdx.x * blockDim.x + tid; n < N; n += gridDim.x * blockDim.x) {
        float acc = 0.0f;
        #pragma unroll
        for (int cc = 0; cc < 16; ++cc) acc += x0[n * 16 + cc] * Wout[cc];
        s += acc;
    }
    red[tid] = s;
    __syncthreads();
    for (int off = 128; off > 0; off >>= 1) {
        if (tid < off) red[tid] += red[tid + off];
        __syncthreads();
    }
    if (tid == 0) partial[blockIdx.x] = red[0];
}

__global__ void k_out2(const float* __restrict__ partial, float* __restrict__ out,
                       int nb, float scale) {
    __shared__ float red[256];
    int tid = threadIdx.x;
    red[tid] = (tid < nb) ? partial[tid] : 0.0f;
    __syncthreads();
    for (int off = 128; off > 0; off >>= 1) {
        if (tid < off) red[tid] += red[tid + off];
        __syncthreads();
    }
    if (tid == 0) out[0] = red[0] * scale;
}

extern "C" void kernel_launch(void* const* d_in, const int* in_sizes, int n_in,
                              void* d_out, int out_size, void* d_ws, size_t ws_size,
                              hipStream_t stream) {
    const float* pos = (const float*)d_in[0];
    const float* x   = (const float*)d_in[1];
    const int* esrc  = (const int*)d_in[2];
    const int* edst  = (const int*)d_in[3];
    const float* mlp_w1 = (const float*)d_in[5];
    const float* mlp_b1 = (const float*)d_in[6];
    const float* mlp_w2 = (const float*)d_in[7];
    const float* P0  = (const float*)d_in[8];
    const float* Wsc = (const float*)d_in[9];
    const float* Wa  = (const float*)d_in[10];
    const float* Wout = (const float*)d_in[13];
    int N = in_sizes[0] / 3;
    int E = in_sizes[2];
    int nbuck = (N + 127) >> 7;
    int cap = E + 512 * nbuck + 256;

    char* ws = (char*)d_ws;
    size_t off = 0;
    auto alloc = [&](size_t bytes) -> void* {
        void* p = ws + off;
        off += (bytes + 255) & ~(size_t)255;
        return p;
    };
    int*      row_start = (int*)alloc((size_t)N * 4);
    int*      rlen      = (int*)alloc((size_t)N * 4);
    int*      bhist     = (int*)alloc(512 * 4);
    int*      bbase     = (int*)alloc(513 * 4);
    int*      bcursor   = (int*)alloc(512 * 4);
    unsigned* csr       = (unsigned*)alloc((size_t)cap * 4);
    __half*   tbh       = (__half*)alloc((size_t)3 * TSZ2 * 16 * 2);
    __half*   p0A = (__half*)alloc((size_t)65536 * 16 * 2);   // src is 16-bit: index-safe
    __half*   p0B = (__half*)alloc((size_t)65536 * 16 * 2);
    float*    x0A = (float*)alloc((size_t)N * 16 * 4);
    float*    x0B = (float*)alloc((size_t)N * 16 * 4);
    uint2*    bbuf = (uint2*)alloc((size_t)E * 8);
    float*    partial = (float*)alloc(256 * 4);

    int nchunk = (E + CHK - 1) / CHK;

    k_table<<<3 * (TSZ2 / 32), 256, 0, stream>>>(mlp_w1, mlp_b1, mlp_w2, tbh, bhist);
    k_hist<<<nchunk, 256, 0, stream>>>(edst, bhist, E, x, P0, p0A, N);
    k_bscan<<<1, 512, 0, stream>>>(bhist, bbase, bcursor, nbuck, E);
    k_scat1<<<nchunk, 256, 0, stream>>>(pos, esrc, edst, bcursor, bbuf, E, nbuck);
    k_scat2<<<nbuck, 256, 0, stream>>>(bbuf, bbase, csr, row_start, rlen, N);

    float* x0bufs[2] = {x0A, x0B};
    __half* p0bufs[2] = {p0A, p0B};
    for (int l = 0; l < 3; ++l) {
        const float* x0c = (l == 0) ? x : x0bufs[l & 1];
        float* x0n = x0bufs[(l & 1) ^ 1];
        const __half* p0c = p0bufs[l & 1];
        __half* p0n = p0bufs[(l & 1) ^ 1];
        const float* P0next = (l < 2) ? (P0 + (l + 1) * 256) : P0;
        k_aggupd<<<(N + 3) / 4, 256, 0, stream>>>(
            row_start, rlen, csr, tbh + (size_t)l * TSZ2 * 16, p0c,
            x0c, x0n, p0n,
            Wsc + l * 768, Wa + l * 768, P0next, N, (l < 2) ? 1 : 0);
    }
    float scale = (float)(1.0 / sqrt((double)N));
    k_out1<<<256, 256, 0, stream>>>(x0bufs[1], Wout, partial, N);
    k_out2<<<1, 256, 0, stream>>>(partial, (float*)d_out, 256, scale);
}

// Round 15
// 160.022 us; speedup vs baseline: 3.1177x; 1.0457x over previous
//
#include <hip/hip_runtime.h>
#include <hip/hip_fp16.h>
#include <math.h>

#define TSZ2 4096
#define RMAXF 2.0f
#define NBAS 10
#define HID 100
#define CHK 4096   // edges per binning block

__device__ __forceinline__ float sigmoidf_(float z) { return 1.0f / (1.0f + __expf(-z)); }

// ---------------- radial table (ONLY w0: first 16 MLP outputs), fp16 [l][t][c] ----------------
// also zeroes bhist (runs before k_hist)
__global__ void k_table(const float* __restrict__ w1, const float* __restrict__ b1,
                        const float* __restrict__ w2, __half* __restrict__ tbh,
                        int* __restrict__ bhist) {
    int gtid = blockIdx.x * 256 + threadIdx.x;
    if (gtid < 512) bhist[gtid] = 0;

    int l = blockIdx.x >> 7;
    int t0 = (blockIdx.x & 127) * 32;
    __shared__ float emb[32][NBAS];
    __shared__ float h[32][HID];
    __shared__ float w2s[HID * 16];
    int tid = threadIdx.x;
    for (int i = tid; i < HID * 16; i += 256) {
        int k = i >> 4, j = i & 15;
        w2s[i] = w2[l * HID * 48 + k * 48 + j];   // only first 16 output cols are live
    }
    for (int i = tid; i < 32 * NBAS; i += 256) {
        int tt = i / NBAS, bi = i % NBAS;
        float r = (16.0f * (t0 + tt) + 7.5f) * (RMAXF / 65535.0f);
        float d = (r - (bi + 0.5f) * 0.2f) * 5.0f;
        emb[tt][bi] = (fabsf(d) < 1.0f) ? cosf(1.5707963267948966f * d) * 3.1622776601683795f : 0.0f;
    }
    __syncthreads();
    for (int i = tid; i < 32 * HID; i += 256) {
        int tt = i / HID, hh = i % HID;
        float z = b1[l * HID + hh];
        #pragma unroll
        for (int bi = 0; bi < NBAS; ++bi) z += emb[tt][bi] * w1[(l * NBAS + bi) * HID + hh];
        h[tt][hh] = z * sigmoidf_(z);
    }
    __syncthreads();
    for (int i = tid; i < 32 * 16; i += 256) {
        int tt = i >> 4, j = i & 15;
        int t = t0 + tt;
        float o = 0.0f;
        if (t != TSZ2 - 1) {   // last row stays zero = sentinel
            for (int k = 0; k < HID; ++k) o += h[tt][k] * w2s[k * 16 + j];
        }
        tbh[((size_t)l * TSZ2 + t) * 16 + j] = __float2half(o);
    }
}

// ---------------- bucket histogram (LDS-agg) + fused p0 (layer 0, fp16); 1024 threads ----------------
__launch_bounds__(1024)
__global__ void k_hist(const int* __restrict__ edst, int* bhist, int E,
                       const float* __restrict__ x0, const float* __restrict__ P0l,
                       __half* __restrict__ p0, int N) {
    __shared__ int lb[512];
    int tid = threadIdx.x;
    for (int i = tid; i < 512; i += 1024) lb[i] = 0;
    __syncthreads();
    int e0 = blockIdx.x * CHK;
    #pragma unroll
    for (int k = 0; k < CHK / 1024; ++k) {
        int e = e0 + k * 1024 + tid;
        if (e < E) atomicAdd(&lb[edst[e] >> 7], 1);
    }
    // fused p0 = x0 @ P0[0]
    for (int i = blockIdx.x * 1024 + tid; i < N * 16; i += gridDim.x * 1024) {
        int n = i >> 4, m = i & 15;
        float acc = 0.0f;
        #pragma unroll
        for (int c = 0; c < 16; ++c) acc += x0[n * 16 + c] * P0l[c * 16 + m];
        p0[i] = __float2half(acc);
    }
    __syncthreads();
    if (tid < 512 && lb[tid]) atomicAdd(&bhist[tid], lb[tid]);
}

// ---------------- bucket scan (1 block, 512 threads) ----------------
__global__ void k_bscan(const int* __restrict__ bhist, int* __restrict__ bbase,
                        int* __restrict__ bcursor, int nbuck, int E) {
    __shared__ int part[512];
    int t = threadIdx.x;
    part[t] = (t < nbuck) ? bhist[t] : 0;
    __syncthreads();
    for (int off = 1; off < 512; off <<= 1) {
        int v = (t >= off) ? part[t - off] : 0;
        __syncthreads();
        part[t] += v;
        __syncthreads();
    }
    int ex = (t == 0) ? 0 : part[t - 1];
    if (t < nbuck) { bbase[t] = ex; bcursor[t] = ex; }
    if (t == 0) bbase[nbuck] = E;
}

// ---------------- phase 1: bin edges into dst-buckets, 8B entries; 1024 threads ----------------
__launch_bounds__(1024)
__global__ void k_scat1(const float* __restrict__ pos, const int* __restrict__ esrc,
                        const int* __restrict__ edst, int* __restrict__ bcursor,
                        uint2* __restrict__ bbuf, int E, int nbuck) {
    __shared__ int lcnt[512];
    __shared__ int base[512];
    int tid = threadIdx.x;
    for (int i = tid; i < 512; i += 1024) lcnt[i] = 0;
    __syncthreads();
    int e0 = blockIdx.x * CHK;
    #pragma unroll
    for (int k = 0; k < CHK / 1024; ++k) {
        int e = e0 + k * 1024 + tid;
        if (e < E) atomicAdd(&lcnt[edst[e] >> 7], 1);
    }
    __syncthreads();
    if (tid < 512 && tid < nbuck)
        base[tid] = lcnt[tid] ? atomicAdd(&bcursor[tid], lcnt[tid]) : 0;
    __syncthreads();
    #pragma unroll
    for (int k = 0; k < CHK / 1024; ++k) {
        int e = e0 + k * 1024 + tid;
        if (e >= E) continue;
        int s = esrc[e], d = edst[e];
        float vx = pos[s * 3 + 0] - pos[d * 3 + 0];
        float vy = pos[s * 3 + 1] - pos[d * 3 + 1];
        float vz = pos[s * 3 + 2] - pos[d * 3 + 2];
        float r = sqrtf(vx * vx + vy * vy + vz * vz);
        unsigned rtfix = (unsigned)fminf(r * (65535.0f / RMAXF) + 0.5f, 65535.0f);
        uint2 o;
        o.x = (unsigned)s | (rtfix << 16);
        o.y = (unsigned)d;
        int slot = atomicAdd(&base[d >> 7], 1);
        bbuf[slot] = o;
    }
}

// ---------------- phase 2: bucket counting-sort -> padded CSR(4B) + row_start/rlen + padfill ----------------
__global__ void k_scat2(const uint2* __restrict__ bbuf, const int* __restrict__ bbase,
                        unsigned* __restrict__ csr, int* __restrict__ row_start,
                        int* __restrict__ rlen, int N) {
    int b = blockIdx.x;
    int tid = threadIdx.x;
    __shared__ int cnt128[128];
    __shared__ int base128[128];
    __shared__ int cur[128];
    __shared__ int part[128];
    if (tid < 128) cnt128[tid] = 0;
    __syncthreads();
    int j0 = bbase[b], j1 = bbase[b + 1];
    int n0 = b << 7;
    for (int j = j0 + tid; j < j1; j += 256)
        atomicAdd(&cnt128[((int)bbuf[j].y) & 127], 1);
    __syncthreads();
    if (tid < 128) part[tid] = (cnt128[tid] + 3) & ~3;
    __syncthreads();
    for (int off = 1; off < 128; off <<= 1) {
        int v = 0;
        if (tid < 128 && tid >= off) v = part[tid - off];
        __syncthreads();
        if (tid < 128) part[tid] += v;
        __syncthreads();
    }
    int pbase = j0 + 512 * b;   // padded base: bbase[b] + per-bucket pad slack
    if (tid < 128) {
        int ex = pbase + ((tid == 0) ? 0 : part[tid - 1]);
        base128[tid] = ex;
        cur[tid] = ex;
        int n = n0 + tid;
        if (n < N) {
            row_start[n] = ex;
            rlen[n] = (cnt128[tid] + 3) & ~3;
        }
    }
    __syncthreads();
    for (int j = j0 + tid; j < j1; j += 256) {
        uint2 e = bbuf[j];
        int local = ((int)e.y) & 127;
        int slot = atomicAdd(&cur[local], 1);
        csr[slot] = e.x;
    }
    __syncthreads();
    // sentinel padfill (<=3 per node): rtfix=0xFFFF -> table row 4095 = zeros
    if (tid < 128) {
        int end = base128[tid] + ((cnt128[tid] + 3) & ~3);
        for (int s = cur[tid]; s < end; ++s) csr[s] = 0xFFFF0000u;
    }
}

// ---------------- fused aggregation + node update; wave per node, x0-path only ----------------
__launch_bounds__(256)
__global__ void k_aggupd(const int* __restrict__ row_start, const int* __restrict__ rlen,
                         const unsigned* __restrict__ csr,
                         const __half* __restrict__ tbh, const __half* __restrict__ p0g,
                         const float* __restrict__ x0c,
                         float* __restrict__ x0n, __half* __restrict__ p0out,
                         const float* __restrict__ Wsc, const float* __restrict__ Wa,
                         const float* __restrict__ P0n,
                         int N, int wp0) {
    const float INVS = 0.17677669529663687f;  // 1/sqrt(32)
    __shared__ unsigned ROW[4][96];   // 64-edge DMA window + prefetch overrun slack
    int tid = threadIdx.x;
    int wid = tid >> 6;
    int lane = tid & 63;
    int n = blockIdx.x * 4 + wid;
    if (n >= N) return;
    int g = lane >> 4, c = lane & 15;
    float a0 = 0.0f;
    float xr0 = 0.0f;
    if (lane < 16) xr0 = x0c[(size_t)n * 16 + lane];
    int e0 = row_start[n];
    int plen = rlen[n];
    if (plen > 0) {
        __builtin_amdgcn_global_load_lds(
            (const __attribute__((address_space(1))) void*)(csr + e0 + lane),
            (__attribute__((address_space(3))) void*)(&ROW[wid][0]), 4, 0, 0);
        asm volatile("s_waitcnt vmcnt(0)" ::: "memory");
        const unsigned* RB = ROW[wid];
        int L = plen >> 2;               // pad-4 rows: exact group count
        int Lm = L < 16 ? L : 16;        // LDS window covers 64 edges
        unsigned c0 = RB[g], c1 = RB[4 + g], c2v = RB[8 + g], c3 = RB[12 + g];
        float p0v = __half2float(p0g[(c0 & 0xffffu) * 16 + c]);
        float w0v = __half2float(tbh[(c0 >> 20) * 16 + c]);
        float p1v = __half2float(p0g[(c1 & 0xffffu) * 16 + c]);
        float w1v = __half2float(tbh[(c1 >> 20) * 16 + c]);
        float p2v = __half2float(p0g[(c2v & 0xffffu) * 16 + c]);
        float w2v = __half2float(tbh[(c2v >> 20) * 16 + c]);
        #pragma unroll 2
        for (int k = 0; k < Lm; ++k) {
            unsigned c4 = RB[(k + 4) * 4 + g];
            float p3v = __half2float(p0g[(c3 & 0xffffu) * 16 + c]);
            float w3v = __half2float(tbh[(c3 >> 20) * 16 + c]);
            a0 += w0v * p0v;
            c0 = c1; c1 = c2v; c2v = c3; c3 = c4;
            p0v = p1v; w0v = w1v;
            p1v = p2v; w1v = w2v;
            p2v = p3v; w2v = w3v;
        }
        if (plen > 64) {   // rare fallback beyond LDS window (Poisson(32): ~never)
            for (int j = e0 + 64 + g; j < e0 + plen; j += 4) {
                unsigned cx = csr[j];
                a0 += __half2float(tbh[(cx >> 20) * 16 + c]) *
                      __half2float(p0g[(cx & 0xffffu) * 16 + c]);
            }
        }
    }
    // reduce over the 4 edge slots (lane bits 4,5); lane&15 = channel
    a0 += __shfl_xor(a0, 16);
    a0 += __shfl_xor(a0, 32);
    a0 *= INVS;
    // tail: s_j = sum_cc x0[cc]*Wsc[cc*48+j] + agg0[cc]*Wa[cc*48+j]; split cc over 4 slots
    float sj = 0.0f;
    #pragma unroll
    for (int t = 0; t < 4; ++t) {
        int cc = g * 4 + t;
        float xv = __shfl(xr0, cc);
        float av = __shfl(a0, cc);
        sj += xv * Wsc[cc * 48 + c] + av * Wa[cc * 48 + c];
    }
    sj += __shfl_xor(sj, 16);
    sj += __shfl_xor(sj, 32);
    float act = sj * sigmoidf_(sj);
    if (lane < 16) x0n[(size_t)n * 16 + lane] = act;
    // p0 for next layer
    if (wp0) {
        float pn = 0.0f;
        #pragma unroll
        for (int t = 0; t < 4; ++t) {
            int cc = g * 4 + t;
            float av = __shfl(act, cc);
            pn += av * P0n[cc * 16 + c];
        }
        pn += __shfl_xor(pn, 16);
        pn += __shfl_xor(pn, 32);
        if (lane < 16) p0out[(size_t)n * 16 + lane] = __float2half(pn);
    }
}

// ---------------- final reduction ----------------
__global__ void k_out1(const float* __restrict__ x0, const float* __restrict__ Wout,
                       float* __restrict__ partial, int N) {
    __shared__ float red[256];
    int tid = threadIdx.x;
    float s = 0.0f;
    for (int n = blockIdx.x * blockDim.x + tid; n < N; n += gridDim.x * blockDim.x) {
        float acc = 0.0f;
        #pragma unroll
        for (int cc = 0; cc < 16; ++cc) acc += x0[n * 16 + cc] * Wout[cc];
        s += acc;
    }
    red[tid] = s;
    __syncthreads();
    for (int off = 128; off > 0; off >>= 1) {
        if (tid < off) red[tid] += red[tid + off];
        __syncthreads();
    }
    if (tid == 0) partial[blockIdx.x] = red[0];
}

__global__ void k_out2(const float* __restrict__ partial, float* __restrict__ out,
                       int nb, float scale) {
    __shared__ float red[256];
    int tid = threadIdx.x;
    red[tid] = (tid < nb) ? partial[tid] : 0.0f;
    __syncthreads();
    for (int off = 128; off > 0; off >>= 1) {
        if (tid < off) red[tid] += red[tid + off];
        __syncthreads();
    }
    if (tid == 0) out[0] = red[0] * scale;
}

extern "C" void kernel_launch(void* const* d_in, const int* in_sizes, int n_in,
                              void* d_out, int out_size, void* d_ws, size_t ws_size,
                              hipStream_t stream) {
    const float* pos = (const float*)d_in[0];
    const float* x   = (const float*)d_in[1];
    const int* esrc  = (const int*)d_in[2];
    const int* edst  = (const int*)d_in[3];
    const float* mlp_w1 = (const float*)d_in[5];
    const float* mlp_b1 = (const float*)d_in[6];
    const float* mlp_w2 = (const float*)d_in[7];
    const float* P0  = (const float*)d_in[8];
    const float* Wsc = (const float*)d_in[9];
    const float* Wa  = (const float*)d_in[10];
    const float* Wout = (const float*)d_in[13];
    int N = in_sizes[0] / 3;
    int E = in_sizes[2];
    int nbuck = (N + 127) >> 7;
    int cap = E + 512 * nbuck + 256;

    char* ws = (char*)d_ws;
    size_t off = 0;
    auto alloc = [&](size_t bytes) -> void* {
        void* p = ws + off;
        off += (bytes + 255) & ~(size_t)255;
        return p;
    };
    int*      row_start = (int*)alloc((size_t)N * 4);
    int*      rlen      = (int*)alloc((size_t)N * 4);
    int*      bhist     = (int*)alloc(512 * 4);
    int*      bbase     = (int*)alloc(513 * 4);
    int*      bcursor   = (int*)alloc(512 * 4);
    unsigned* csr       = (unsigned*)alloc((size_t)cap * 4);
    __half*   tbh       = (__half*)alloc((size_t)3 * TSZ2 * 16 * 2);
    __half*   p0A = (__half*)alloc((size_t)65536 * 16 * 2);   // src is 16-bit: index-safe
    __half*   p0B = (__half*)alloc((size_t)65536 * 16 * 2);
    float*    x0A = (float*)alloc((size_t)N * 16 * 4);
    float*    x0B = (float*)alloc((size_t)N * 16 * 4);
    uint2*    bbuf = (uint2*)alloc((size_t)E * 8);
    float*    partial = (float*)alloc(256 * 4);

    int nchunk = (E + CHK - 1) / CHK;

    k_table<<<3 * (TSZ2 / 32), 256, 0, stream>>>(mlp_w1, mlp_b1, mlp_w2, tbh, bhist);
    k_hist<<<nchunk, 1024, 0, stream>>>(edst, bhist, E, x, P0, p0A, N);
    k_bscan<<<1, 512, 0, stream>>>(bhist, bbase, bcursor, nbuck, E);
    k_scat1<<<nchunk, 1024, 0, stream>>>(pos, esrc, edst, bcursor, bbuf, E, nbuck);
    k_scat2<<<nbuck, 256, 0, stream>>>(bbuf, bbase, csr, row_start, rlen, N);

    float* x0bufs[2] = {x0A, x0B};
    __half* p0bufs[2] = {p0A, p0B};
    for (int l = 0; l < 3; ++l) {
        const float* x0c = (l == 0) ? x : x0bufs[l & 1];
        float* x0n = x0bufs[(l & 1) ^ 1];
        const __half* p0c = p0bufs[l & 1];
        __half* p0n = p0bufs[(l & 1) ^ 1];
        const float* P0next = (l < 2) ? (P0 + (l + 1) * 256) : P0;
        k_aggupd<<<(N + 3) / 4, 256, 0, stream>>>(
            row_start, rlen, csr, tbh + (size_t)l * TSZ2 * 16, p0c,
            x0c, x0n, p0n,
            Wsc + l * 768, Wa + l * 768, P0next, N, (l < 2) ? 1 : 0);
    }
    float scale = (float)(1.0 / sqrt((double)N));
    k_out1<<<256, 256, 0, stream>>>(x0bufs[1], Wout, partial, N);
    k_out2<<<1, 256, 0, stream>>>(partial, (float*)d_out, 256, scale);
}

// Round 16
// 159.279 us; speedup vs baseline: 3.1323x; 1.0047x over previous
//
#include <hip/hip_runtime.h>
#include <hip/hip_fp16.h>
#include <math.h>

#define TSZ2 4096
#define RMAXF 2.0f
#define NBAS 10
#define HID 100
#define CHK 2048   // edges per binning block

__device__ __forceinline__ float sigmoidf_(float z) { return 1.0f / (1.0f + __expf(-z)); }

// ---------------- radial table (ONLY w0: first 16 MLP outputs), fp16 [l][t][c] ----------------
__global__ void k_table(const float* __restrict__ w1, const float* __restrict__ b1,
                        const float* __restrict__ w2, __half* __restrict__ tbh) {
    int l = blockIdx.x >> 7;
    int t0 = (blockIdx.x & 127) * 32;
    __shared__ float emb[32][NBAS];
    __shared__ float h[32][HID];
    __shared__ float w2s[HID * 16];
    int tid = threadIdx.x;
    for (int i = tid; i < HID * 16; i += 256) {
        int k = i >> 4, j = i & 15;
        w2s[i] = w2[l * HID * 48 + k * 48 + j];   // only first 16 output cols are live
    }
    for (int i = tid; i < 32 * NBAS; i += 256) {
        int tt = i / NBAS, bi = i % NBAS;
        float r = (16.0f * (t0 + tt) + 7.5f) * (RMAXF / 65535.0f);
        float d = (r - (bi + 0.5f) * 0.2f) * 5.0f;
        emb[tt][bi] = (fabsf(d) < 1.0f) ? cosf(1.5707963267948966f * d) * 3.1622776601683795f : 0.0f;
    }
    __syncthreads();
    for (int i = tid; i < 32 * HID; i += 256) {
        int tt = i / HID, hh = i % HID;
        float z = b1[l * HID + hh];
        #pragma unroll
        for (int bi = 0; bi < NBAS; ++bi) z += emb[tt][bi] * w1[(l * NBAS + bi) * HID + hh];
        h[tt][hh] = z * sigmoidf_(z);
    }
    __syncthreads();
    for (int i = tid; i < 32 * 16; i += 256) {
        int tt = i >> 4, j = i & 15;
        int t = t0 + tt;
        float o = 0.0f;
        if (t != TSZ2 - 1) {   // last row stays zero = sentinel
            for (int k = 0; k < HID; ++k) o += h[tt][k] * w2s[k * 16 + j];
        }
        tbh[((size_t)l * TSZ2 + t) * 16 + j] = __float2half(o);
    }
}

// ---------------- per-block bucket histogram -> bcnt[bucket][blk] + fused p0 ----------------
__launch_bounds__(512)
__global__ void k_hist(const int* __restrict__ edst, int* __restrict__ bcnt, int E, int nblk, int nbuck,
                       const float* __restrict__ x0, const float* __restrict__ P0l,
                       __half* __restrict__ p0, int N) {
    __shared__ int lb[512];
    int tid = threadIdx.x;
    int blk = blockIdx.x;
    lb[tid] = 0;
    __syncthreads();
    int e0 = blk * CHK;
    #pragma unroll
    for (int k = 0; k < CHK / 512; ++k) {
        int e = e0 + k * 512 + tid;
        if (e < E) atomicAdd(&lb[edst[e] >> 7], 1);
    }
    // fused p0 = x0 @ P0[0]
    for (int i = blk * 512 + tid; i < N * 16; i += gridDim.x * 512) {
        int n = i >> 4, m = i & 15;
        float acc = 0.0f;
        #pragma unroll
        for (int c = 0; c < 16; ++c) acc += x0[n * 16 + c] * P0l[c * 16 + m];
        p0[i] = __float2half(acc);
    }
    __syncthreads();
    for (int b = tid; b < nbuck; b += 512) bcnt[(size_t)b * nblk + blk] = lb[b];
}

// ---------------- scan A: per-1024-chunk sums ----------------
__global__ void k_scanA(const int* __restrict__ bcnt, int* __restrict__ bsum, int M) {
    __shared__ int red[256];
    int base = blockIdx.x * 1024;
    int t = threadIdx.x;
    int s = 0;
    #pragma unroll
    for (int k = 0; k < 4; ++k) {
        int i = base + k * 256 + t;
        if (i < M) s += bcnt[i];
    }
    red[t] = s;
    __syncthreads();
    for (int off = 128; off > 0; off >>= 1) {
        if (t < off) red[t] += red[t + off];
        __syncthreads();
    }
    if (t == 0) bsum[blockIdx.x] = red[0];
}

// ---------------- scan B: scan of chunk sums (nb <= 512); also bbase[nbuck]=E ----------------
__global__ void k_scanB(const int* __restrict__ bsum, int* __restrict__ boffA, int nb,
                        int* __restrict__ bbase, int nbuck, int E) {
    __shared__ int part[512];
    int t = threadIdx.x;
    part[t] = (t < nb) ? bsum[t] : 0;
    __syncthreads();
    for (int off = 1; off < 512; off <<= 1) {
        int v = (t >= off) ? part[t - off] : 0;
        __syncthreads();
        part[t] += v;
        __syncthreads();
    }
    if (t < nb) boffA[t] = (t == 0) ? 0 : part[t - 1];
    if (t == 0) bbase[nbuck] = E;
}

// ---------------- scan C: apply -> bofs[blk][bucket] (transposed) + bbase[bucket] ----------------
__global__ void k_scanC(const int* __restrict__ bcnt, const int* __restrict__ boffA,
                        int* __restrict__ bofs, int* __restrict__ bbase,
                        int M, int nblk, int nbuck) {
    __shared__ int part[256];
    int b = blockIdx.x, t = threadIdx.x;
    int base = b * 1024;
    int v[4];
    int s = 0;
    #pragma unroll
    for (int k = 0; k < 4; ++k) {
        int i = base + t * 4 + k;
        v[k] = (i < M) ? bcnt[i] : 0;
        s += v[k];
    }
    part[t] = s;
    __syncthreads();
    for (int off = 1; off < 256; off <<= 1) {
        int x = (t >= off) ? part[t - off] : 0;
        __syncthreads();
        part[t] += x;
        __syncthreads();
    }
    int run = boffA[b] + ((t == 0) ? 0 : part[t - 1]);
    #pragma unroll
    for (int k = 0; k < 4; ++k) {
        int i = base + t * 4 + k;
        if (i < M) {
            int bucket = i / nblk;
            int blk = i - bucket * nblk;
            bofs[(size_t)blk * nbuck + bucket] = run;
            if (blk == 0) bbase[bucket] = run;
            run += v[k];
        }
    }
}

// ---------------- phase 1: scatter edges into dst-buckets; NO global atomics ----------------
__launch_bounds__(512)
__global__ void k_scat1(const float* __restrict__ pos, const int* __restrict__ esrc,
                        const int* __restrict__ edst, const int* __restrict__ bofs,
                        uint2* __restrict__ bbuf, int E, int nbuck) {
    __shared__ int base[512];
    int tid = threadIdx.x;
    int blk = blockIdx.x;
    for (int b = tid; b < nbuck; b += 512) base[b] = bofs[(size_t)blk * nbuck + b];
    __syncthreads();
    int e0 = blk * CHK;
    #pragma unroll
    for (int k = 0; k < CHK / 512; ++k) {
        int e = e0 + k * 512 + tid;
        if (e >= E) continue;
        int s = esrc[e], d = edst[e];
        float vx = pos[s * 3 + 0] - pos[d * 3 + 0];
        float vy = pos[s * 3 + 1] - pos[d * 3 + 1];
        float vz = pos[s * 3 + 2] - pos[d * 3 + 2];
        float r = sqrtf(vx * vx + vy * vy + vz * vz);
        unsigned rtfix = (unsigned)fminf(r * (65535.0f / RMAXF) + 0.5f, 65535.0f);
        uint2 o;
        o.x = (unsigned)s | (rtfix << 16);
        o.y = (unsigned)d;
        int slot = atomicAdd(&base[d >> 7], 1);
        bbuf[slot] = o;
    }
}

// ---------------- phase 2: bucket counting-sort -> padded CSR(4B) + row_start/rlen + padfill ----------------
__global__ void k_scat2(const uint2* __restrict__ bbuf, const int* __restrict__ bbase,
                        unsigned* __restrict__ csr, int* __restrict__ row_start,
                        int* __restrict__ rlen, int N) {
    int b = blockIdx.x;
    int tid = threadIdx.x;
    __shared__ int cnt128[128];
    __shared__ int base128[128];
    __shared__ int cur[128];
    __shared__ int part[128];
    if (tid < 128) cnt128[tid] = 0;
    __syncthreads();
    int j0 = bbase[b], j1 = bbase[b + 1];
    int n0 = b << 7;
    for (int j = j0 + tid; j < j1; j += 256)
        atomicAdd(&cnt128[((int)bbuf[j].y) & 127], 1);
    __syncthreads();
    if (tid < 128) part[tid] = (cnt128[tid] + 3) & ~3;
    __syncthreads();
    for (int off = 1; off < 128; off <<= 1) {
        int v = 0;
        if (tid < 128 && tid >= off) v = part[tid - off];
        __syncthreads();
        if (tid < 128) part[tid] += v;
        __syncthreads();
    }
    int pbase = j0 + 512 * b;   // padded base: bbase[b] + per-bucket pad slack
    if (tid < 128) {
        int ex = pbase + ((tid == 0) ? 0 : part[tid - 1]);
        base128[tid] = ex;
        cur[tid] = ex;
        int n = n0 + tid;
        if (n < N) {
            row_start[n] = ex;
            rlen[n] = (cnt128[tid] + 3) & ~3;
        }
    }
    __syncthreads();
    for (int j = j0 + tid; j < j1; j += 256) {
        uint2 e = bbuf[j];
        int local = ((int)e.y) & 127;
        int slot = atomicAdd(&cur[local], 1);
        csr[slot] = e.x;
    }
    __syncthreads();
    // sentinel padfill (<=3 per node): rtfix=0xFFFF -> table row 4095 = zeros
    if (tid < 128) {
        int end = base128[tid] + ((cnt128[tid] + 3) & ~3);
        for (int s = cur[tid]; s < end; ++s) csr[s] = 0xFFFF0000u;
    }
}

// ---------------- fused aggregation + node update; wave per node, x0-path only ----------------
__launch_bounds__(256)
__global__ void k_aggupd(const int* __restrict__ row_start, const int* __restrict__ rlen,
                         const unsigned* __restrict__ csr,
                         const __half* __restrict__ tbh, const __half* __restrict__ p0g,
                         const float* __restrict__ x0c,
                         float* __restrict__ x0n, __half* __restrict__ p0out,
                         const float* __restrict__ Wsc, const float* __restrict__ Wa,
                         const float* __restrict__ P0n,
                         int N, int wp0) {
    const float INVS = 0.17677669529663687f;  // 1/sqrt(32)
    __shared__ unsigned ROW[4][96];   // 64-edge DMA window + prefetch overrun slack
    int tid = threadIdx.x;
    int wid = tid >> 6;
    int lane = tid & 63;
    int n = blockIdx.x * 4 + wid;
    if (n >= N) return;
    int g = lane >> 4, c = lane & 15;
    float a0 = 0.0f;
    float xr0 = 0.0f;
    if (lane < 16) xr0 = x0c[(size_t)n * 16 + lane];
    int e0 = row_start[n];
    int plen = rlen[n];
    if (plen > 0) {
        __builtin_amdgcn_global_load_lds(
            (const __attribute__((address_space(1))) void*)(csr + e0 + lane),
            (__attribute__((address_space(3))) void*)(&ROW[wid][0]), 4, 0, 0);
        asm volatile("s_waitcnt vmcnt(0)" ::: "memory");
        const unsigned* RB = ROW[wid];
        int L = plen >> 2;               // pad-4 rows: exact group count
        int Lm = L < 16 ? L : 16;        // LDS window covers 64 edges
        unsigned c0 = RB[g], c1 = RB[4 + g], c2v = RB[8 + g], c3 = RB[12 + g];
        float p0v = __half2float(p0g[(c0 & 0xffffu) * 16 + c]);
        float w0v = __half2float(tbh[(c0 >> 20) * 16 + c]);
        float p1v = __half2float(p0g[(c1 & 0xffffu) * 16 + c]);
        float w1v = __half2float(tbh[(c1 >> 20) * 16 + c]);
        float p2v = __half2float(p0g[(c2v & 0xffffu) * 16 + c]);
        float w2v = __half2float(tbh[(c2v >> 20) * 16 + c]);
        #pragma unroll 2
        for (int k = 0; k < Lm; ++k) {
            unsigned c4 = RB[(k + 4) * 4 + g];
            float p3v = __half2float(p0g[(c3 & 0xffffu) * 16 + c]);
            float w3v = __half2float(tbh[(c3 >> 20) * 16 + c]);
            a0 += w0v * p0v;
            c0 = c1; c1 = c2v; c2v = c3; c3 = c4;
            p0v = p1v; w0v = w1v;
            p1v = p2v; w1v = w2v;
            p2v = p3v; w2v = w3v;
        }
        if (plen > 64) {   // rare fallback beyond LDS window (Poisson(32): ~never)
            for (int j = e0 + 64 + g; j < e0 + plen; j += 4) {
                unsigned cx = csr[j];
                a0 += __half2float(tbh[(cx >> 20) * 16 + c]) *
                      __half2float(p0g[(cx & 0xffffu) * 16 + c]);
            }
        }
    }
    // reduce over the 4 edge slots (lane bits 4,5); lane&15 = channel
    a0 += __shfl_xor(a0, 16);
    a0 += __shfl_xor(a0, 32);
    a0 *= INVS;
    // tail: s_j = sum_cc x0[cc]*Wsc[cc*48+j] + agg0[cc]*Wa[cc*48+j]; split cc over 4 slots
    float sj = 0.0f;
    #pragma unroll
    for (int t = 0; t < 4; ++t) {
        int cc = g * 4 + t;
        float xv = __shfl(xr0, cc);
        float av = __shfl(a0, cc);
        sj += xv * Wsc[cc * 48 + c] + av * Wa[cc * 48 + c];
    }
    sj += __shfl_xor(sj, 16);
    sj += __shfl_xor(sj, 32);
    float act = sj * sigmoidf_(sj);
    if (lane < 16) x0n[(size_t)n * 16 + lane] = act;
    // p0 for next layer
    if (wp0) {
        float pn = 0.0f;
        #pragma unroll
        for (int t = 0; t < 4; ++t) {
            int cc = g * 4 + t;
            float av = __shfl(act, cc);
            pn += av * P0n[cc * 16 + c];
        }
        pn += __shfl_xor(pn, 16);
        pn += __shfl_xor(pn, 32);
        if (lane < 16) p0out[(size_t)n * 16 + lane] = __float2half(pn);
    }
}

// ---------------- final reduction ----------------
__global__ void k_out1(const float* __restrict__ x0, const float* __restrict__ Wout,
                       float* __restrict__ partial, int N) {
    __shared__ float red[256];
    int tid = threadIdx.x;
    float s = 0.0f;
    for (int n = blockIdx.x * blockDim.x + tid; n < N; n += gridDim.x * blockDim.x) {
        float acc = 0.0f;
        #pragma unroll
        for (int cc = 0; cc < 16; ++cc) acc += x0[n * 16 + cc] * Wout[cc];
        s += acc;
    }
    red[tid] = s;
    __syncthreads();
    for (int off = 128; off > 0; off >>= 1) {
        if (tid < off) red[tid] += red[tid + off];
        __syncthreads();
    }
    if (tid == 0) partial[blockIdx.x] = red[0];
}

__global__ void k_out2(const float* __restrict__ partial, float* __restrict__ out,
                       int nb, float scale) {
    __shared__ float red[256];
    int tid = threadIdx.x;
    red[tid] = (tid < nb) ? partial[tid] : 0.0f;
    __syncthreads();
    for (int off = 128; off > 0; off >>= 1) {
        if (tid < off) red[tid] += red[tid + off];
        __syncthreads();
    }
    if (tid == 0) out[0] = red[0] * scale;
}

extern "C" void kernel_launch(void* const* d_in, const int* in_sizes, int n_in,
                              void* d_out, int out_size, void* d_ws, size_t ws_size,
                              hipStream_t stream) {
    const float* pos = (const float*)d_in[0];
    const float* x   = (const float*)d_in[1];
    const int* esrc  = (const int*)d_in[2];
    const int* edst  = (const int*)d_in[3];
    const float* mlp_w1 = (const float*)d_in[5];
    const float* mlp_b1 = (const float*)d_in[6];
    const float* mlp_w2 = (const float*)d_in[7];
    const float* P0  = (const float*)d_in[8];
    const float* Wsc = (const float*)d_in[9];
    const float* Wa  = (const float*)d_in[10];
    const float* Wout = (const float*)d_in[13];
    int N = in_sizes[0] / 3;
    int E = in_sizes[2];
    int nbuck = (N + 127) >> 7;
    int nblk = (E + CHK - 1) / CHK;
    int M = nbuck * nblk;
    int cap = E + 512 * nbuck + 256;
    int nscan = (M + 1023) / 1024;

    char* ws = (char*)d_ws;
    size_t off = 0;
    auto alloc = [&](size_t bytes) -> void* {
        void* p = ws + off;
        off += (bytes + 255) & ~(size_t)255;
        return p;
    };
    int*      row_start = (int*)alloc((size_t)N * 4);
    int*      rlen      = (int*)alloc((size_t)N * 4);
    int*      bbase     = (int*)alloc(513 * 4);
    int*      bsum      = (int*)alloc(512 * 4);
    int*      boffA     = (int*)alloc(512 * 4);
    int*      bcnt      = (int*)alloc((size_t)M * 4);
    int*      bofs      = (int*)alloc((size_t)M * 4);
    unsigned* csr       = (unsigned*)alloc((size_t)cap * 4);
    __half*   tbh       = (__half*)alloc((size_t)3 * TSZ2 * 16 * 2);
    __half*   p0A = (__half*)alloc((size_t)65536 * 16 * 2);   // src is 16-bit: index-safe
    __half*   p0B = (__half*)alloc((size_t)65536 * 16 * 2);
    float*    x0A = (float*)alloc((size_t)N * 16 * 4);
    float*    x0B = (float*)alloc((size_t)N * 16 * 4);
    uint2*    bbuf = (uint2*)alloc((size_t)E * 8);
    float*    partial = (float*)alloc(256 * 4);

    k_table<<<3 * (TSZ2 / 32), 256, 0, stream>>>(mlp_w1, mlp_b1, mlp_w2, tbh);
    k_hist<<<nblk, 512, 0, stream>>>(edst, bcnt, E, nblk, nbuck, x, P0, p0A, N);
    k_scanA<<<nscan, 256, 0, stream>>>(bcnt, bsum, M);
    k_scanB<<<1, 512, 0, stream>>>(bsum, boffA, nscan, bbase, nbuck, E);
    k_scanC<<<nscan, 256, 0, stream>>>(bcnt, boffA, bofs, bbase, M, nblk, nbuck);
    k_scat1<<<nblk, 512, 0, stream>>>(pos, esrc, edst, bofs, bbuf, E, nbuck);
    k_scat2<<<nbuck, 256, 0, stream>>>(bbuf, bbase, csr, row_start, rlen, N);

    float* x0bufs[2] = {x0A, x0B};
    __half* p0bufs[2] = {p0A, p0B};
    for (int l = 0; l < 3; ++l) {
        const float* x0c = (l == 0) ? x : x0bufs[l & 1];
        float* x0n = x0bufs[(l & 1) ^ 1];
        const __half* p0c = p0bufs[l & 1];
        __half* p0n = p0bufs[(l & 1) ^ 1];
        const float* P0next = (l < 2) ? (P0 + (l + 1) * 256) : P0;
        k_aggupd<<<(N + 3) / 4, 256, 0, stream>>>(
            row_start, rlen, csr, tbh + (size_t)l * TSZ2 * 16, p0c,
            x0c, x0n, p0n,
            Wsc + l * 768, Wa + l * 768, P0next, N, (l < 2) ? 1 : 0);
    }
    float scale = (float)(1.0 / sqrt((double)N));
    k_out1<<<256, 256, 0, stream>>>(x0bufs[1], Wout, partial, N);
    k_out2<<<1, 256, 0, stream>>>(partial, (float*)d_out, 256, scale);
}